// Round 3
// baseline (787.792 us; speedup 1.0000x reference)
//
#include <hip/hip_runtime.h>
#include <math.h>

#define NN 10000
#define NE 160000
#define MUL 128
#define ADIM 10
#define RADF 8
#define HID 64
#define INV_SQRT3 0.57735026918962576f
#define NCHUNK 4
#define NPC 2500           // nodes per chunk
#define CAP 44032          // max edges per chunk buffer

typedef __attribute__((ext_vector_type(8))) short bf16x8;
typedef __attribute__((ext_vector_type(4))) float f32x4;

__device__ __forceinline__ float silu_f(float x){ return x / (1.0f + __expf(-x)); }
__device__ __forceinline__ float sigmoid_f(float x){ return 1.0f / (1.0f + __expf(-x)); }
__device__ __forceinline__ unsigned short f2b(float f){
  union{float f; unsigned u;} v; v.f=f;
  unsigned r = (v.u + 0x7fffu + ((v.u>>16)&1u))>>16;
  return (unsigned short)r;
}
__device__ __forceinline__ float b2f(unsigned short h){
  union{unsigned u; float f;} v; v.u = ((unsigned)h)<<16; return v.f;
}

// ---------------- K0: src/tgt embeddings (N,10)@(10,128) -> bf16 ----------------
__global__ __launch_bounds__(256) void k_emb(
    const float* __restrict__ attrs, const float* __restrict__ Ws,
    const float* __restrict__ Wt, unsigned short* __restrict__ se, unsigned short* __restrict__ te){
  int idx = blockIdx.x*256 + threadIdx.x;
  if (idx >= NN*MUL) return;
  int n = idx >> 7, v = idx & 127;
  float as=0.f, at=0.f;
  #pragma unroll
  for (int a=0;a<ADIM;a++){
    float x = attrs[n*ADIM+a];
    as += x*Ws[a*MUL+v];
    at += x*Wt[a*MUL+v];
  }
  se[idx]=f2b(as); te[idx]=f2b(at);
}

// ---------------- feat prep: split feats into contiguous bf16 s / v_i ----------------
__global__ __launch_bounds__(256) void k_feat_prep(
    const float* __restrict__ feats, unsigned short* __restrict__ fs16,
    unsigned short* __restrict__ fv16){
  int idx = blockIdx.x*256 + threadIdx.x;   // over NN*512
  int n = idx >> 9, c = idx & 511;
  float v = feats[idx];
  if (c < 128) fs16[n*128 + c] = f2b(v);
  else {
    int q = c - 128; int u = q/3; int i = q - 3*u;
    fv16[((size_t)n*3 + i)*128 + u] = f2b(v);
  }
}

// ---------------- weight prep: transpose + bf16 cast ----------------
__global__ __launch_bounds__(256) void k_prep(
    const float* __restrict__ Wr1, const float* __restrict__ Wd1,
    const float* __restrict__ Wr2, const float* __restrict__ Wr3,
    const float* __restrict__ Wr4,
    const float* __restrict__ Wl10, const float* __restrict__ Wl11,
    const float* __restrict__ Wl20, const float* __restrict__ Wl21,
    const float* __restrict__ Wsk0, const float* __restrict__ Wup0, const float* __restrict__ Wres0,
    const float* __restrict__ Wsk1, const float* __restrict__ Wup1, const float* __restrict__ Wres1,
    unsigned short* __restrict__ WTr1, unsigned short* __restrict__ WTd1,
    unsigned short* __restrict__ WTr2, unsigned short* __restrict__ WTr3,
    unsigned short* __restrict__ WTr4,
    unsigned short* __restrict__ Wl10T, unsigned short* __restrict__ Wl11T,
    unsigned short* __restrict__ Wl20T, unsigned short* __restrict__ Wl21T,
    unsigned short* __restrict__ WnsT, unsigned short* __restrict__ WnvT){
  int idx = blockIdx.x*256 + threadIdx.x;
  if (idx < 18432){
    int n = idx/288, k = idx - n*288;
    WTr1[idx] = (k<264)? f2b(Wr1[k*64+n]) : (unsigned short)0;
  } else if (idx < 36864){
    int j = idx-18432; int n=j/288, k=j-n*288;
    WTd1[j] = (k<264)? f2b(Wd1[k*64+n]) : (unsigned short)0;
  } else if (idx < 40960){
    int j = idx-36864; int n=j>>6, k=j&63;
    WTr2[j] = f2b(Wr2[k*64+n]);
  } else if (idx < 45056){
    int j = idx-40960; int n=j>>6, k=j&63;
    WTr3[j] = f2b(Wr3[k*64+n]);
  } else if (idx < 77824){
    int j = idx-45056; int n=j>>6, k=j&63;
    WTr4[j] = f2b(Wr4[k*512+n]);
  } else if (idx < 143360){
    int j = idx-77824; int n=j>>8, k=j&255;
    Wl10T[j] = f2b(Wl10[k*256+n]);
  } else if (idx < 176128){
    int j = idx-143360; int n=j>>8, k=j&255;
    Wl11T[j] = f2b(Wl11[k*128+n]);
  } else if (idx < 192512){
    int j = idx-176128; int n=j>>7, k=j&127;
    Wl20T[j] = f2b(Wl20[k*128+n]);
  } else if (idx < 208896){
    int j = idx-192512; int n=j>>7, k=j&127;
    Wl21T[j] = f2b(Wl21[k*128+n]);
  } else if (idx < 274432){
    int j = idx-208896; int n=j>>7, k=j&127;
    float v;
    if (n < 128)      v = Wsk0[k*128+n];
    else if (n < 256) v = Wup0[k*128+(n-128)];
    else              v = Wres0[k*256+(n-256)];
    WnsT[j] = f2b(v);
  } else if (idx < 323584){
    int j = idx-274432; int n=j>>7, k=j&127;
    float v;
    if (n < 128)      v = Wsk1[k*128+n];
    else if (n < 256) v = Wup1[k*128+(n-128)];
    else              v = Wres1[k*128+(n-256)];
    WnvT[j] = f2b(v);
  }
}

// ---------------- K1: per-node precompute (skip/up/res) via MFMA ----------------
__global__ __launch_bounds__(256) void k_node_pre2(
    const unsigned short* __restrict__ fs16, const unsigned short* __restrict__ fv16,
    const unsigned short* __restrict__ WnsT, const unsigned short* __restrict__ WnvT,
    float* __restrict__ out_sc,
    unsigned short* __restrict__ up_s, unsigned short* __restrict__ up_v,
    float* __restrict__ res_s, float* __restrict__ res_v){
  __shared__ unsigned short fA[64][136];
  int nb = blockIdx.x*64;
  int tid = threadIdx.x;
  int w = tid>>6, l = tid&63, m0 = w*16, lr = l&15, lg = l>>4;
  for (int g=0; g<4; ++g){
    if (g) __syncthreads();
    for (int idx=tid; idx<64*16; idx+=256){
      int row = idx>>4, s8 = idx&15;
      int n = min(nb+row, NN-1);
      const unsigned short* src = (g==0) ? &fs16[(size_t)n*128 + s8*8]
                                         : &fv16[((size_t)n*3 + (g-1))*128 + s8*8];
      *(uint4*)&fA[row][s8*8] = *(const uint4*)src;
    }
    __syncthreads();
    const unsigned short* WT = (g==0)? WnsT : WnvT;
    int nchunks = (g==0)? 4 : 3;
    for (int ntc=0; ntc<nchunks; ++ntc){
      f32x4 acc[8];
      #pragma unroll
      for (int t=0;t<8;t++) acc[t]=(f32x4)(0.f);
      #pragma unroll
      for (int kb=0;kb<4;kb++){
        bf16x8 a = *(const bf16x8*)&fA[m0+lr][kb*32 + lg*8];
        #pragma unroll
        for (int t=0;t<8;t++){
          bf16x8 b = *(const bf16x8*)&WT[((size_t)((ntc*8+t)*16+lr))*128 + kb*32 + lg*8];
          acc[t] = __builtin_amdgcn_mfma_f32_16x16x32_bf16(a, b, acc[t], 0,0,0);
        }
      }
      #pragma unroll
      for (int t=0;t<8;t++){
        #pragma unroll
        for (int r=0;r<4;r++){
          int col = (ntc*8+t)*16 + lr;
          int row = m0 + lg*4 + r;
          int n = nb + row;
          if (n < NN){
            float v = acc[t][r];
            if (g==0){
              if (col < 128)      out_sc[(size_t)n*512 + col] = v;
              else if (col < 256) up_s[(size_t)n*128 + col-128] = f2b(v);
              else                res_s[(size_t)n*256 + col-256] = v;
            } else {
              int i = g-1;
              if (col < 128)      out_sc[(size_t)n*512 + 128 + col*3 + i] = v;
              else if (col < 256) up_v[((size_t)n*3+i)*128 + col-128] = f2b(v);
              else                res_v[((size_t)n*3+i)*128 + col-256] = v;
            }
          }
        }
      }
    }
  }
}

// ---------------- CSR build ----------------
__global__ __launch_bounds__(256) void k_deg(const int* __restrict__ eidx, int* __restrict__ deg){
  int i = blockIdx.x*256+threadIdx.x;
  if (i<NE) atomicAdd(&deg[eidx[2*i+1]],1);
}
__global__ __launch_bounds__(256) void k_scan(const int* __restrict__ deg, int* __restrict__ offsets){
  __shared__ int part[256];
  int t = threadIdx.x; int base = t*40;
  int s=0;
  for (int k=0;k<40;k++){ int idx=base+k; if (idx<NN) s+=deg[idx]; }
  part[t]=s; __syncthreads();
  if (t==0){ int run=0; for (int i=0;i<256;i++){ int v=part[i]; part[i]=run; run+=v; } }
  __syncthreads();
  int run = part[t];
  for (int k=0;k<40;k++){
    int idx=base+k;
    if (idx<=NN) offsets[idx]=run;
    if (idx<NN) run+=deg[idx];
  }
}
__global__ __launch_bounds__(256) void k_fill(const int* __restrict__ eidx, const int* __restrict__ offsets,
                                              int* __restrict__ cursor, int* __restrict__ elist){
  int i = blockIdx.x*256+threadIdx.x;
  if (i<NE){ int r = eidx[2*i+1]; int p = atomicAdd(&cursor[r],1); elist[offsets[r]+p]=i; }
}

// ---------------- K2: batched MFMA edge MLP -> tpw (bf16) + edge density ----------------
__global__ __launch_bounds__(256) void k_tpw(
    const int* __restrict__ elist, const int* __restrict__ eidx,
    const float* __restrict__ ef, const float* __restrict__ ea,
    const unsigned short* __restrict__ se, const unsigned short* __restrict__ te,
    const unsigned short* __restrict__ WTr1, const unsigned short* __restrict__ WTd1,
    const unsigned short* __restrict__ WTr2, const unsigned short* __restrict__ WTr3,
    const unsigned short* __restrict__ WTr4, const float* __restrict__ Wd2,
    const int* __restrict__ offsets, int nstart, int nend,
    unsigned short* __restrict__ tpw, float4* __restrict__ ybuf,
    int* __restrict__ sndbuf, float* __restrict__ densbuf){
  __shared__ unsigned short aug[64][296];
  __shared__ unsigned short hA[64][72];
  __shared__ unsigned short hB[64][72];
  __shared__ int s_e[64], s_snd[64], s_rcv[64];
  int ebase = offsets[nstart];
  int eend  = min(offsets[nend], ebase + CAP);
  int i0 = ebase + blockIdx.x*64;
  if (i0 >= eend) return;
  int nrows = min(64, eend - i0);
  int tid = threadIdx.x;
  int w = tid>>6, l = tid&63;
  if (tid < 64){
    int ii = min(i0 + tid, eend-1);
    int e = elist[ii];
    s_e[tid]=e;
    int sn = eidx[2*e], rc = eidx[2*e+1];
    s_snd[tid]=sn; s_rcv[tid]=rc;
    if (tid < nrows){
      int li = i0 - ebase + tid;
      sndbuf[li] = sn;
      ybuf[li] = ((const float4*)ea)[e];
    }
  }
  __syncthreads();
  {
    int r = tid>>2, q = tid&3;
    int e = s_e[r], sn = s_snd[r], rc = s_rcv[r];
    for (int c=q*66; c<q*66+66; ++c){
      unsigned short v;
      if (c < 8)        v = f2b(ef[e*8 + c]);
      else if (c < 136) v = se[sn*128 + (c-8)];
      else              v = te[rc*128 + (c-136)];
      aug[r][c] = v;
    }
    if (q==3){ for (int c=264;c<296;++c) aug[r][c]=0; }
  }
  __syncthreads();
  int m0 = w*16;
  int lr = l&15, lg = l>>4;
  // ---- layer1 (rad) + den1, K=288 ----
  f32x4 acc[4], accd[4];
  #pragma unroll
  for (int nt=0;nt<4;nt++){ acc[nt]=(f32x4)(0.f); accd[nt]=(f32x4)(0.f); }
  for (int kb=0;kb<9;kb++){
    bf16x8 a = *(const bf16x8*)&aug[m0+lr][kb*32 + lg*8];
    #pragma unroll
    for (int nt=0;nt<4;nt++){
      bf16x8 b  = *(const bf16x8*)&WTr1[(nt*16+lr)*288 + kb*32 + lg*8];
      bf16x8 bd = *(const bf16x8*)&WTd1[(nt*16+lr)*288 + kb*32 + lg*8];
      acc[nt]  = __builtin_amdgcn_mfma_f32_16x16x32_bf16(a, b,  acc[nt],  0,0,0);
      accd[nt] = __builtin_amdgcn_mfma_f32_16x16x32_bf16(a, bd, accd[nt], 0,0,0);
    }
  }
  float d0=0,d1=0,d2=0,d3=0;
  #pragma unroll
  for (int nt=0;nt<4;nt++){
    float wd2v = Wd2[nt*16+lr];
    #pragma unroll
    for (int r=0;r<4;r++){
      hA[m0+lg*4+r][nt*16+lr] = f2b(silu_f(acc[nt][r]));
      float sv = silu_f(accd[nt][r]) * wd2v;
      if (r==0) d0+=sv; else if (r==1) d1+=sv; else if (r==2) d2+=sv; else d3+=sv;
    }
  }
  #pragma unroll
  for (int m=1;m<16;m<<=1){
    d0 += __shfl_xor(d0, m); d1 += __shfl_xor(d1, m);
    d2 += __shfl_xor(d2, m); d3 += __shfl_xor(d3, m);
  }
  if (lr < 4){
    float dv = (lr==0)?d0:(lr==1)?d1:(lr==2)?d2:d3;
    int row = m0 + lg*4 + lr;
    if (row < nrows) densbuf[i0 - ebase + row] = tanhf(dv*dv);
  }
  // (no barrier: hA rows m0..m0+15 are wave-private)
  // ---- layer2: hA -> hB ----
  #pragma unroll
  for (int nt=0;nt<4;nt++) acc[nt]=(f32x4)(0.f);
  for (int kb=0;kb<2;kb++){
    bf16x8 a = *(const bf16x8*)&hA[m0+lr][kb*32 + lg*8];
    #pragma unroll
    for (int nt=0;nt<4;nt++){
      bf16x8 b = *(const bf16x8*)&WTr2[(nt*16+lr)*64 + kb*32 + lg*8];
      acc[nt] = __builtin_amdgcn_mfma_f32_16x16x32_bf16(a, b, acc[nt], 0,0,0);
    }
  }
  #pragma unroll
  for (int nt=0;nt<4;nt++)
    #pragma unroll
    for (int r=0;r<4;r++)
      hB[m0+lg*4+r][nt*16+lr] = f2b(silu_f(acc[nt][r]));
  // ---- layer3: hB -> hA ----
  #pragma unroll
  for (int nt=0;nt<4;nt++) acc[nt]=(f32x4)(0.f);
  for (int kb=0;kb<2;kb++){
    bf16x8 a = *(const bf16x8*)&hB[m0+lr][kb*32 + lg*8];
    #pragma unroll
    for (int nt=0;nt<4;nt++){
      bf16x8 b = *(const bf16x8*)&WTr3[(nt*16+lr)*64 + kb*32 + lg*8];
      acc[nt] = __builtin_amdgcn_mfma_f32_16x16x32_bf16(a, b, acc[nt], 0,0,0);
    }
  }
  #pragma unroll
  for (int nt=0;nt<4;nt++)
    #pragma unroll
    for (int r=0;r<4;r++)
      hA[m0+lg*4+r][nt*16+lr] = f2b(silu_f(acc[nt][r]));
  // ---- layer4 (no activation), N=512 in 8 chunks of 64, wave-private restage ----
  int li0 = i0 - ebase + m0;
  for (int g=0; g<8; g++){
    f32x4 a4[4];
    #pragma unroll
    for (int nt=0;nt<4;nt++) a4[nt]=(f32x4)(0.f);
    for (int kb=0;kb<2;kb++){
      bf16x8 a = *(const bf16x8*)&hA[m0+lr][kb*32 + lg*8];
      #pragma unroll
      for (int nt=0;nt<4;nt++){
        bf16x8 b = *(const bf16x8*)&WTr4[(g*64+nt*16+lr)*64 + kb*32 + lg*8];
        a4[nt] = __builtin_amdgcn_mfma_f32_16x16x32_bf16(a, b, a4[nt], 0,0,0);
      }
    }
    #pragma unroll
    for (int nt=0;nt<4;nt++)
      #pragma unroll
      for (int r=0;r<4;r++)
        hB[m0+lg*4+r][nt*16+lr] = f2b(a4[nt][r]);
    {
      int row = l>>2, seg = l&3;
      if (m0 + row < nrows){
        const uint4* srcp = (const uint4*)&hB[m0+row][seg*16];
        uint4 v0 = srcp[0], v1 = srcp[1];
        uint4* dst = (uint4*)&tpw[((size_t)(li0+row)*8 + g)*64 + seg*16];
        dst[0]=v0; dst[1]=v1;
      }
    }
  }
}

// ---------------- K3: CSR gather (no atomics) -> bf16 messages ----------------
__global__ __launch_bounds__(256) void k_gather(
    const unsigned short* __restrict__ tpw, const float4* __restrict__ ybuf,
    const int* __restrict__ sndbuf, const float* __restrict__ densbuf,
    const unsigned short* __restrict__ up_s, const unsigned short* __restrict__ up_v,
    const int* __restrict__ offsets, int nstart,
    unsigned short* __restrict__ msg_s16, unsigned short* __restrict__ msg_v16,
    float* __restrict__ density){
  int w = threadIdx.x>>6, l = threadIdx.x&63;
  int n = nstart + blockIdx.x*4 + w;
  if (n >= NN) return;
  int ebase = offsets[nstart];
  int s0 = offsets[n], s1 = offsets[n+1];
  float mA0=0,mA1=0,mD0=0,mD1=0;
  float mB00=0,mB01=0,mB10=0,mB11=0,mB20=0,mB21=0;
  float mC00=0,mC01=0,mC10=0,mC11=0,mC20=0,mC21=0;
  float dsum=0;
  #pragma unroll 2
  for (int i=s0;i<s1;++i){
    int li = i - ebase;
    int sn = sndbuf[li];
    float4 y = ybuf[li];
    dsum += densbuf[li];
    const unsigned short* tp = tpw + (size_t)li*512;
    float wA0=b2f(tp[l]),     wA1=b2f(tp[64+l]);
    float wB0=b2f(tp[128+l]), wB1=b2f(tp[192+l]);
    float wC0=b2f(tp[256+l]), wC1=b2f(tp[320+l]);
    float wD0=b2f(tp[384+l]), wD1=b2f(tp[448+l]);
    const unsigned short* us = up_s + (size_t)sn*128;
    float xs0=b2f(us[l]), xs1=b2f(us[64+l]);
    const unsigned short* uv = up_v + (size_t)sn*384;
    float xv00=b2f(uv[l]),     xv01=b2f(uv[64+l]);
    float xv10=b2f(uv[128+l]), xv11=b2f(uv[192+l]);
    float xv20=b2f(uv[256+l]), xv21=b2f(uv[320+l]);
    mA0 += wA0*xs0*y.x; mA1 += wA1*xs1*y.x;
    float dot0 = xv00*y.y + xv10*y.z + xv20*y.w;
    float dot1 = xv01*y.y + xv11*y.z + xv21*y.w;
    mD0 += wD0*dot0; mD1 += wD1*dot1;
    float b0 = wB0*xs0, b1 = wB1*xs1;
    mB00 += b0*y.y; mB01 += b1*y.y;
    mB10 += b0*y.z; mB11 += b1*y.z;
    mB20 += b0*y.w; mB21 += b1*y.w;
    float c0 = wC0*y.x, c1 = wC1*y.x;
    mC00 += c0*xv00; mC01 += c1*xv01;
    mC10 += c0*xv10; mC11 += c1*xv11;
    mC20 += c0*xv20; mC21 += c1*xv21;
  }
  unsigned short* ms = msg_s16 + (size_t)n*256;
  ms[l]=f2b(mA0); ms[64+l]=f2b(mA1);
  ms[128+l]=f2b(mD0*INV_SQRT3); ms[192+l]=f2b(mD1*INV_SQRT3);
  unsigned short* mv = msg_v16 + (size_t)n*768;
  mv[l]=f2b(mB00);     mv[64+l]=f2b(mB01);  mv[128+l]=f2b(mC00); mv[192+l]=f2b(mC01);
  mv[256+l]=f2b(mB10); mv[320+l]=f2b(mB11); mv[384+l]=f2b(mC10); mv[448+l]=f2b(mC11);
  mv[512+l]=f2b(mB20); mv[576+l]=f2b(mB21); mv[640+l]=f2b(mC20); mv[704+l]=f2b(mC21);
  if (l==0) density[n]=dsum;
}

// ---------------- K4: fused node post (lin1 -> act/gate -> lin2) via MFMA ----------------
__global__ __launch_bounds__(256) void k_node_post(
    const unsigned short* __restrict__ msg_s16, const unsigned short* __restrict__ msg_v16,
    const float* __restrict__ density,
    const float* __restrict__ res_s, const float* __restrict__ res_v,
    const unsigned short* __restrict__ Wl10T, const unsigned short* __restrict__ Wl11T,
    const unsigned short* __restrict__ Wl20T, const unsigned short* __restrict__ Wl21T,
    const float* __restrict__ alphap, const float* __restrict__ betap,
    float* __restrict__ out_msg){
  __shared__ unsigned short sm[64][264];
  __shared__ unsigned short sg[64][264];
  __shared__ float sden[64];
  int nb = blockIdx.x*64;
  int tid = threadIdx.x;
  int w = tid>>6, l = tid&63, m0 = w*16, lr = l&15, lg = l>>4;
  for (int idx=tid; idx<64*32; idx+=256){
    int row = idx>>5, s8 = idx&31;
    int n = min(nb+row, NN-1);
    *(uint4*)&sm[row][s8*8] = *(const uint4*)&msg_s16[(size_t)n*256 + s8*8];
  }
  if (tid < 64){
    int n = min(nb+tid, NN-1);
    sden[tid] = density[n]*betap[0] + alphap[0]*20.0f;
  }
  __syncthreads();
  // GEMM1a: msg_s @ Wl10 (K=256, N=256)
  {
    f32x4 acc[16];
    #pragma unroll
    for (int t=0;t<16;t++) acc[t]=(f32x4)(0.f);
    for (int kb=0;kb<8;kb++){
      bf16x8 a = *(const bf16x8*)&sm[m0+lr][kb*32 + lg*8];
      #pragma unroll
      for (int t=0;t<16;t++){
        bf16x8 b = *(const bf16x8*)&Wl10T[(size_t)((t*16+lr))*256 + kb*32 + lg*8];
        acc[t] = __builtin_amdgcn_mfma_f32_16x16x32_bf16(a, b, acc[t], 0,0,0);
      }
    }
    #pragma unroll
    for (int t=0;t<16;t++){
      #pragma unroll
      for (int r=0;r<4;r++){
        int col = t*16+lr;
        int row = m0 + lg*4 + r;
        int n = nb + row;
        int nn = min(n, NN-1);
        float v = acc[t][r]/sden[row] + res_s[(size_t)nn*256 + col];
        float rr = (col < 128) ? silu_f(v) : sigmoid_f(v);
        sg[row][col] = f2b(rr);
      }
    }
  }
  // GEMM2a: scal @ Wl20 (K=128, N=128) — sg rows are wave-private, no barrier needed
  {
    f32x4 acc[8];
    #pragma unroll
    for (int t=0;t<8;t++) acc[t]=(f32x4)(0.f);
    #pragma unroll
    for (int kb=0;kb<4;kb++){
      bf16x8 a = *(const bf16x8*)&sg[m0+lr][kb*32 + lg*8];
      #pragma unroll
      for (int t=0;t<8;t++){
        bf16x8 b = *(const bf16x8*)&Wl20T[(size_t)((t*16+lr))*128 + kb*32 + lg*8];
        acc[t] = __builtin_amdgcn_mfma_f32_16x16x32_bf16(a, b, acc[t], 0,0,0);
      }
    }
    #pragma unroll
    for (int t=0;t<8;t++){
      #pragma unroll
      for (int r=0;r<4;r++){
        int col = t*16+lr;
        int n = nb + m0 + lg*4 + r;
        if (n < NN) out_msg[(size_t)n*512 + col*4] = acc[t][r];
      }
    }
  }
  // vector components
  for (int i=0;i<3;i++){
    __syncthreads();
    for (int idx=tid; idx<64*32; idx+=256){
      int row = idx>>5, s8 = idx&31;
      int n = min(nb+row, NN-1);
      *(uint4*)&sm[row][s8*8] = *(const uint4*)&msg_v16[(size_t)n*768 + i*256 + s8*8];
    }
    __syncthreads();
    f32x4 acc[8];
    #pragma unroll
    for (int t=0;t<8;t++) acc[t]=(f32x4)(0.f);
    for (int kb=0;kb<8;kb++){
      bf16x8 a = *(const bf16x8*)&sm[m0+lr][kb*32 + lg*8];
      #pragma unroll
      for (int t=0;t<8;t++){
        bf16x8 b = *(const bf16x8*)&Wl11T[(size_t)((t*16+lr))*256 + kb*32 + lg*8];
        acc[t] = __builtin_amdgcn_mfma_f32_16x16x32_bf16(a, b, acc[t], 0,0,0);
      }
    }
    #pragma unroll
    for (int t=0;t<8;t++){
      #pragma unroll
      for (int r=0;r<4;r++){
        int col = t*16+lr;
        int row = m0 + lg*4 + r;
        int n = nb + row;
        int nn = min(n, NN-1);
        float v = acc[t][r]/sden[row] + res_v[((size_t)nn*3+i)*128 + col];
        v *= b2f(sg[row][128+col]);
        sm[row][col] = f2b(v);   // wave-private rows: safe overwrite after own reads
      }
    }
    // GEMM2b: vec_i @ Wl21
    f32x4 a2[8];
    #pragma unroll
    for (int t=0;t<8;t++) a2[t]=(f32x4)(0.f);
    #pragma unroll
    for (int kb=0;kb<4;kb++){
      bf16x8 a = *(const bf16x8*)&sm[m0+lr][kb*32 + lg*8];
      #pragma unroll
      for (int t=0;t<8;t++){
        bf16x8 b = *(const bf16x8*)&Wl21T[(size_t)((t*16+lr))*128 + kb*32 + lg*8];
        a2[t] = __builtin_amdgcn_mfma_f32_16x16x32_bf16(a, b, a2[t], 0,0,0);
      }
    }
    #pragma unroll
    for (int t=0;t<8;t++){
      #pragma unroll
      for (int r=0;r<4;r++){
        int col = t*16+lr;
        int n = nb + m0 + lg*4 + r;
        if (n < NN) out_msg[(size_t)n*512 + col*4 + 1 + i] = a2[t][r];
      }
    }
  }
}

extern "C" void kernel_launch(void* const* d_in, const int* in_sizes, int n_in,
                              void* d_out, int out_size, void* d_ws, size_t ws_size,
                              hipStream_t stream){
  (void)in_sizes; (void)n_in; (void)out_size; (void)ws_size;
  const float* attrs = (const float*)d_in[0];
  const float* feats = (const float*)d_in[1];
  const float* ea    = (const float*)d_in[2];
  const float* ef    = (const float*)d_in[3];
  const float* Wsrc  = (const float*)d_in[4];
  const float* Wtgt  = (const float*)d_in[5];
  const float* Wup0  = (const float*)d_in[6];
  const float* Wup1  = (const float*)d_in[7];
  const float* Wsk0  = (const float*)d_in[8];
  const float* Wsk1  = (const float*)d_in[9];
  const float* Wres0 = (const float*)d_in[10];
  const float* Wres1 = (const float*)d_in[11];
  const float* Wl10  = (const float*)d_in[12];
  const float* Wl11  = (const float*)d_in[13];
  const float* Wl20  = (const float*)d_in[14];
  const float* Wl21  = (const float*)d_in[15];
  const float* Wr1   = (const float*)d_in[16];
  const float* Wr2   = (const float*)d_in[17];
  const float* Wr3   = (const float*)d_in[18];
  const float* Wr4   = (const float*)d_in[19];
  const float* Wd1   = (const float*)d_in[20];
  const float* Wd2   = (const float*)d_in[21];
  const float* alphap= (const float*)d_in[22];
  const float* betap = (const float*)d_in[23];
  const int*   eidx  = (const int*)d_in[24];

  char* p = (char*)d_ws;
  auto alloc = [&](size_t bytes)->char*{ char* r=p; p += (bytes+255)&~(size_t)255; return r; };
  unsigned short* tpw  = (unsigned short*)alloc((size_t)CAP*512*2);
  unsigned short* msg_s16 = (unsigned short*)alloc((size_t)NN*256*2);
  unsigned short* msg_v16 = (unsigned short*)alloc((size_t)NN*768*2);
  float*  res_s   = (float*)alloc((size_t)NN*256*4);
  float*  res_v   = (float*)alloc((size_t)NN*384*4);
  float*  density = (float*)alloc((size_t)NN*4);
  float4* ybuf    = (float4*)alloc((size_t)CAP*16);
  float*  densbuf = (float*)alloc((size_t)CAP*4);
  int*    sndbuf  = (int*)alloc((size_t)CAP*4);
  unsigned short* se16 = (unsigned short*)alloc((size_t)NN*128*2);
  unsigned short* te16 = (unsigned short*)alloc((size_t)NN*128*2);
  unsigned short* up_s16 = (unsigned short*)alloc((size_t)NN*128*2);
  unsigned short* up_v16 = (unsigned short*)alloc((size_t)NN*384*2);
  unsigned short* fs16 = (unsigned short*)alloc((size_t)NN*128*2);
  unsigned short* fv16 = (unsigned short*)alloc((size_t)NN*384*2);
  unsigned short* WTr1 = (unsigned short*)alloc(18432*2);
  unsigned short* WTd1 = (unsigned short*)alloc(18432*2);
  unsigned short* WTr2 = (unsigned short*)alloc(4096*2);
  unsigned short* WTr3 = (unsigned short*)alloc(4096*2);
  unsigned short* WTr4 = (unsigned short*)alloc(32768*2);
  unsigned short* Wl10T = (unsigned short*)alloc(65536*2);
  unsigned short* Wl11T = (unsigned short*)alloc(32768*2);
  unsigned short* Wl20T = (unsigned short*)alloc(16384*2);
  unsigned short* Wl21T = (unsigned short*)alloc(16384*2);
  unsigned short* WnsT  = (unsigned short*)alloc(65536*2);
  unsigned short* WnvT  = (unsigned short*)alloc(49152*2);
  int* deg     = (int*)alloc(10240*4);
  int* cursor  = (int*)alloc(10240*4);
  int* offsets = (int*)alloc(10256*4);
  int* elist   = (int*)alloc((size_t)NE*4);

  float* out_msg = (float*)d_out;               // NN*512
  float* out_sc  = out_msg + (size_t)NN*512;    // NN*512

  hipMemsetAsync(deg, 0, 2*10240*sizeof(int), stream);

  k_prep<<<1264, 256, 0, stream>>>(Wr1, Wd1, Wr2, Wr3, Wr4,
                                   Wl10, Wl11, Wl20, Wl21,
                                   Wsk0, Wup0, Wres0, Wsk1, Wup1, Wres1,
                                   WTr1, WTd1, WTr2, WTr3, WTr4,
                                   Wl10T, Wl11T, Wl20T, Wl21T, WnsT, WnvT);
  k_emb<<<(NN*MUL+255)/256, 256, 0, stream>>>(attrs, Wsrc, Wtgt, se16, te16);
  k_feat_prep<<<NN*512/256, 256, 0, stream>>>(feats, fs16, fv16);
  k_node_pre2<<<(NN+63)/64, 256, 0, stream>>>(fs16, fv16, WnsT, WnvT,
                                              out_sc, up_s16, up_v16, res_s, res_v);
  k_deg<<<(NE+255)/256, 256, 0, stream>>>(eidx, deg);
  k_scan<<<1, 256, 0, stream>>>(deg, offsets);
  k_fill<<<(NE+255)/256, 256, 0, stream>>>(eidx, offsets, cursor, elist);

  for (int c=0; c<NCHUNK; ++c){
    k_tpw<<<CAP/64, 256, 0, stream>>>(elist, eidx, ef, ea, se16, te16,
                                      WTr1, WTd1, WTr2, WTr3, WTr4, Wd2,
                                      offsets, c*NPC, (c+1)*NPC,
                                      tpw, ybuf, sndbuf, densbuf);
    k_gather<<<NPC/4, 256, 0, stream>>>(tpw, ybuf, sndbuf, densbuf, up_s16, up_v16,
                                        offsets, c*NPC, msg_s16, msg_v16, density);
  }

  k_node_post<<<(NN+63)/64, 256, 0, stream>>>(msg_s16, msg_v16, density, res_s, res_v,
                                              Wl10T, Wl11T, Wl20T, Wl21T,
                                              alphap, betap, out_msg);
}

// Round 4
// 684.910 us; speedup vs baseline: 1.1502x; 1.1502x over previous
//
#include <hip/hip_runtime.h>
#include <math.h>

#define NN 10000
#define NE 160000
#define MUL 128
#define ADIM 10
#define RADF 8
#define HID 64
#define INV_SQRT3 0.57735026918962576f
#define NCHUNK 4
#define NPC 2500           // nodes per chunk
#define CAP 44032          // max edges per chunk buffer
#define NB64 157           // ceil(NN/64)

typedef __attribute__((ext_vector_type(8))) short bf16x8;
typedef __attribute__((ext_vector_type(4))) float f32x4;

__device__ __forceinline__ float silu_f(float x){ return x / (1.0f + __expf(-x)); }
__device__ __forceinline__ float sigmoid_f(float x){ return 1.0f / (1.0f + __expf(-x)); }
__device__ __forceinline__ unsigned short f2b(float f){
  union{float f; unsigned u;} v; v.f=f;
  unsigned r = (v.u + 0x7fffu + ((v.u>>16)&1u))>>16;
  return (unsigned short)r;
}
__device__ __forceinline__ float b2f(unsigned short h){
  union{unsigned u; float f;} v; v.u = ((unsigned)h)<<16; return v.f;
}

// ---------------- K0: src/tgt embeddings (N,10)@(10,128) -> bf16 ----------------
__global__ __launch_bounds__(256) void k_emb(
    const float* __restrict__ attrs, const float* __restrict__ Ws,
    const float* __restrict__ Wt, unsigned short* __restrict__ se, unsigned short* __restrict__ te){
  int idx = blockIdx.x*256 + threadIdx.x;
  if (idx >= NN*MUL) return;
  int n = idx >> 7, v = idx & 127;
  float as=0.f, at=0.f;
  #pragma unroll
  for (int a=0;a<ADIM;a++){
    float x = attrs[n*ADIM+a];
    as += x*Ws[a*MUL+v];
    at += x*Wt[a*MUL+v];
  }
  se[idx]=f2b(as); te[idx]=f2b(at);
}

// ---------------- feat prep: split feats into contiguous bf16 s / v_i ----------------
__global__ __launch_bounds__(256) void k_feat_prep(
    const float* __restrict__ feats, unsigned short* __restrict__ fs16,
    unsigned short* __restrict__ fv16){
  int idx = blockIdx.x*256 + threadIdx.x;   // over NN*512
  int n = idx >> 9, c = idx & 511;
  float v = feats[idx];
  if (c < 128) fs16[n*128 + c] = f2b(v);
  else {
    int q = c - 128; int u = q/3; int i = q - 3*u;
    fv16[((size_t)n*3 + i)*128 + u] = f2b(v);
  }
}

// ---------------- weight prep: transpose + bf16 cast ----------------
__global__ __launch_bounds__(256) void k_prep(
    const float* __restrict__ Wr1, const float* __restrict__ Wd1,
    const float* __restrict__ Wr2, const float* __restrict__ Wr3,
    const float* __restrict__ Wr4,
    const float* __restrict__ Wl10, const float* __restrict__ Wl11,
    const float* __restrict__ Wl20, const float* __restrict__ Wl21,
    const float* __restrict__ Wsk0, const float* __restrict__ Wup0, const float* __restrict__ Wres0,
    const float* __restrict__ Wsk1, const float* __restrict__ Wup1, const float* __restrict__ Wres1,
    unsigned short* __restrict__ WTr1, unsigned short* __restrict__ WTd1,
    unsigned short* __restrict__ WTr2, unsigned short* __restrict__ WTr3,
    unsigned short* __restrict__ WTr4,
    unsigned short* __restrict__ Wl10T, unsigned short* __restrict__ Wl11T,
    unsigned short* __restrict__ Wl20T, unsigned short* __restrict__ Wl21T,
    unsigned short* __restrict__ WnsT, unsigned short* __restrict__ WnvT){
  int idx = blockIdx.x*256 + threadIdx.x;
  if (idx < 18432){
    int n = idx/288, k = idx - n*288;
    WTr1[idx] = (k<264)? f2b(Wr1[k*64+n]) : (unsigned short)0;
  } else if (idx < 36864){
    int j = idx-18432; int n=j/288, k=j-n*288;
    WTd1[j] = (k<264)? f2b(Wd1[k*64+n]) : (unsigned short)0;
  } else if (idx < 40960){
    int j = idx-36864; int n=j>>6, k=j&63;
    WTr2[j] = f2b(Wr2[k*64+n]);
  } else if (idx < 45056){
    int j = idx-40960; int n=j>>6, k=j&63;
    WTr3[j] = f2b(Wr3[k*64+n]);
  } else if (idx < 77824){
    int j = idx-45056; int n=j>>6, k=j&63;
    WTr4[j] = f2b(Wr4[k*512+n]);
  } else if (idx < 143360){
    int j = idx-77824; int n=j>>8, k=j&255;
    Wl10T[j] = f2b(Wl10[k*256+n]);
  } else if (idx < 176128){
    int j = idx-143360; int n=j>>8, k=j&255;
    Wl11T[j] = f2b(Wl11[k*128+n]);
  } else if (idx < 192512){
    int j = idx-176128; int n=j>>7, k=j&127;
    Wl20T[j] = f2b(Wl20[k*128+n]);
  } else if (idx < 208896){
    int j = idx-192512; int n=j>>7, k=j&127;
    Wl21T[j] = f2b(Wl21[k*128+n]);
  } else if (idx < 274432){
    int j = idx-208896; int n=j>>7, k=j&127;
    float v;
    if (n < 128)      v = Wsk0[k*128+n];
    else if (n < 256) v = Wup0[k*128+(n-128)];
    else              v = Wres0[k*256+(n-256)];
    WnsT[j] = f2b(v);
  } else if (idx < 323584){
    int j = idx-274432; int n=j>>7, k=j&127;
    float v;
    if (n < 128)      v = Wsk1[k*128+n];
    else if (n < 256) v = Wup1[k*128+(n-128)];
    else              v = Wres1[k*128+(n-256)];
    WnvT[j] = f2b(v);
  }
}

// ---------------- K1: per-node precompute (skip/up/res) via MFMA ----------------
// grid (NB64, 13): blockIdx.y -> (g, ntc) chunk. g=0: 4 chunks; g=1..3: 3 each.
__global__ __launch_bounds__(256) void k_node_pre2(
    const unsigned short* __restrict__ fs16, const unsigned short* __restrict__ fv16,
    const unsigned short* __restrict__ WnsT, const unsigned short* __restrict__ WnvT,
    float* __restrict__ out_sc,
    unsigned short* __restrict__ up_s, unsigned short* __restrict__ up_v,
    float* __restrict__ res_s, float* __restrict__ res_v){
  __shared__ unsigned short fA[64][136];
  int nb = blockIdx.x*64;
  int c = blockIdx.y;
  int g, ntc;
  if (c < 4){ g=0; ntc=c; } else { g = 1 + (c-4)/3; ntc = (c-4)%3; }
  int tid = threadIdx.x;
  int w = tid>>6, l = tid&63, m0 = w*16, lr = l&15, lg = l>>4;
  for (int idx=tid; idx<64*16; idx+=256){
    int row = idx>>4, s8 = idx&15;
    int n = min(nb+row, NN-1);
    const unsigned short* src = (g==0) ? &fs16[(size_t)n*128 + s8*8]
                                       : &fv16[((size_t)n*3 + (g-1))*128 + s8*8];
    *(uint4*)&fA[row][s8*8] = *(const uint4*)src;
  }
  __syncthreads();
  const unsigned short* WT = ((g==0)? WnsT : WnvT) + (size_t)ntc*128*128;
  f32x4 acc[8];
  #pragma unroll
  for (int t=0;t<8;t++) acc[t]=(f32x4)(0.f);
  #pragma unroll
  for (int kb=0;kb<4;kb++){
    bf16x8 a = *(const bf16x8*)&fA[m0+lr][kb*32 + lg*8];
    #pragma unroll
    for (int t=0;t<8;t++){
      bf16x8 b = *(const bf16x8*)&WT[(size_t)(t*16+lr)*128 + kb*32 + lg*8];
      acc[t] = __builtin_amdgcn_mfma_f32_16x16x32_bf16(a, b, acc[t], 0,0,0);
    }
  }
  #pragma unroll
  for (int t=0;t<8;t++){
    #pragma unroll
    for (int r=0;r<4;r++){
      int col = (ntc*8+t)*16 + lr;
      int row = m0 + lg*4 + r;
      int n = nb + row;
      if (n < NN){
        float v = acc[t][r];
        if (g==0){
          if (col < 128)      out_sc[(size_t)n*512 + col] = v;
          else if (col < 256) up_s[(size_t)n*128 + col-128] = f2b(v);
          else                res_s[(size_t)n*256 + col-256] = v;
        } else {
          int i = g-1;
          if (col < 128)      out_sc[(size_t)n*512 + 128 + col*3 + i] = v;
          else if (col < 256) up_v[((size_t)n*3+i)*128 + col-128] = f2b(v);
          else                res_v[((size_t)n*3+i)*128 + col-256] = v;
        }
      }
    }
  }
}

// ---------------- CSR build ----------------
__global__ __launch_bounds__(256) void k_deg(const int* __restrict__ eidx, int* __restrict__ deg){
  int i = blockIdx.x*256+threadIdx.x;
  if (i<NE) atomicAdd(&deg[eidx[2*i+1]],1);
}
__global__ __launch_bounds__(256) void k_scan(const int* __restrict__ deg, int* __restrict__ offsets){
  __shared__ int part[256];
  int t = threadIdx.x; int base = t*40;
  int s=0;
  for (int k=0;k<40;k++){ int idx=base+k; if (idx<NN) s+=deg[idx]; }
  part[t]=s; __syncthreads();
  if (t==0){ int run=0; for (int i=0;i<256;i++){ int v=part[i]; part[i]=run; run+=v; } }
  __syncthreads();
  int run = part[t];
  for (int k=0;k<40;k++){
    int idx=base+k;
    if (idx<=NN) offsets[idx]=run;
    if (idx<NN) run+=deg[idx];
  }
}
__global__ __launch_bounds__(256) void k_fill(const int* __restrict__ eidx, const int* __restrict__ offsets,
                                              int* __restrict__ cursor, int* __restrict__ elist){
  int i = blockIdx.x*256+threadIdx.x;
  if (i<NE){ int r = eidx[2*i+1]; int p = atomicAdd(&cursor[r],1); elist[offsets[r]+p]=i; }
}

// ---------------- K2: batched MFMA edge MLP -> tpw (bf16) + edge density ----------------
__global__ __launch_bounds__(256) void k_tpw(
    const int* __restrict__ elist, const int* __restrict__ eidx,
    const float* __restrict__ ef, const float* __restrict__ ea,
    const unsigned short* __restrict__ se, const unsigned short* __restrict__ te,
    const unsigned short* __restrict__ WTr1, const unsigned short* __restrict__ WTd1,
    const unsigned short* __restrict__ WTr2, const unsigned short* __restrict__ WTr3,
    const unsigned short* __restrict__ WTr4, const float* __restrict__ Wd2,
    const int* __restrict__ offsets, int nstart, int nend,
    unsigned short* __restrict__ tpw, float4* __restrict__ ybuf,
    int* __restrict__ sndbuf, float* __restrict__ densbuf){
  __shared__ unsigned short aug[64][296];
  __shared__ unsigned short hA[64][72];
  __shared__ unsigned short hB[64][72];
  __shared__ int s_e[64], s_snd[64], s_rcv[64];
  int ebase = offsets[nstart];
  int eend  = min(offsets[nend], ebase + CAP);
  int i0 = ebase + blockIdx.x*64;
  if (i0 >= eend) return;
  int nrows = min(64, eend - i0);
  int tid = threadIdx.x;
  int w = tid>>6, l = tid&63;
  if (tid < 64){
    int ii = min(i0 + tid, eend-1);
    int e = elist[ii];
    s_e[tid]=e;
    int sn = eidx[2*e], rc = eidx[2*e+1];
    s_snd[tid]=sn; s_rcv[tid]=rc;
    if (tid < nrows){
      int li = i0 - ebase + tid;
      sndbuf[li] = sn;
      ybuf[li] = ((const float4*)ea)[e];
    }
  }
  __syncthreads();
  {
    int r = tid>>2, q = tid&3;
    int e = s_e[r], sn = s_snd[r], rc = s_rcv[r];
    for (int c=q*66; c<q*66+66; ++c){
      unsigned short v;
      if (c < 8)        v = f2b(ef[e*8 + c]);
      else if (c < 136) v = se[sn*128 + (c-8)];
      else              v = te[rc*128 + (c-136)];
      aug[r][c] = v;
    }
    if (q==3){ for (int c=264;c<296;++c) aug[r][c]=0; }
  }
  __syncthreads();
  int m0 = w*16;
  int lr = l&15, lg = l>>4;
  // ---- layer1 (rad) + den1, K=288 ----
  f32x4 acc[4], accd[4];
  #pragma unroll
  for (int nt=0;nt<4;nt++){ acc[nt]=(f32x4)(0.f); accd[nt]=(f32x4)(0.f); }
  for (int kb=0;kb<9;kb++){
    bf16x8 a = *(const bf16x8*)&aug[m0+lr][kb*32 + lg*8];
    #pragma unroll
    for (int nt=0;nt<4;nt++){
      bf16x8 b  = *(const bf16x8*)&WTr1[(nt*16+lr)*288 + kb*32 + lg*8];
      bf16x8 bd = *(const bf16x8*)&WTd1[(nt*16+lr)*288 + kb*32 + lg*8];
      acc[nt]  = __builtin_amdgcn_mfma_f32_16x16x32_bf16(a, b,  acc[nt],  0,0,0);
      accd[nt] = __builtin_amdgcn_mfma_f32_16x16x32_bf16(a, bd, accd[nt], 0,0,0);
    }
  }
  float d0=0,d1=0,d2=0,d3=0;
  #pragma unroll
  for (int nt=0;nt<4;nt++){
    float wd2v = Wd2[nt*16+lr];
    #pragma unroll
    for (int r=0;r<4;r++){
      hA[m0+lg*4+r][nt*16+lr] = f2b(silu_f(acc[nt][r]));
      float sv = silu_f(accd[nt][r]) * wd2v;
      if (r==0) d0+=sv; else if (r==1) d1+=sv; else if (r==2) d2+=sv; else d3+=sv;
    }
  }
  #pragma unroll
  for (int m=1;m<16;m<<=1){
    d0 += __shfl_xor(d0, m); d1 += __shfl_xor(d1, m);
    d2 += __shfl_xor(d2, m); d3 += __shfl_xor(d3, m);
  }
  if (lr < 4){
    float dv = (lr==0)?d0:(lr==1)?d1:(lr==2)?d2:d3;
    int row = m0 + lg*4 + lr;
    if (row < nrows) densbuf[i0 - ebase + row] = tanhf(dv*dv);
  }
  // ---- layer2: hA -> hB (wave-private rows, no barrier) ----
  #pragma unroll
  for (int nt=0;nt<4;nt++) acc[nt]=(f32x4)(0.f);
  for (int kb=0;kb<2;kb++){
    bf16x8 a = *(const bf16x8*)&hA[m0+lr][kb*32 + lg*8];
    #pragma unroll
    for (int nt=0;nt<4;nt++){
      bf16x8 b = *(const bf16x8*)&WTr2[(nt*16+lr)*64 + kb*32 + lg*8];
      acc[nt] = __builtin_amdgcn_mfma_f32_16x16x32_bf16(a, b, acc[nt], 0,0,0);
    }
  }
  #pragma unroll
  for (int nt=0;nt<4;nt++)
    #pragma unroll
    for (int r=0;r<4;r++)
      hB[m0+lg*4+r][nt*16+lr] = f2b(silu_f(acc[nt][r]));
  // ---- layer3: hB -> hA ----
  #pragma unroll
  for (int nt=0;nt<4;nt++) acc[nt]=(f32x4)(0.f);
  for (int kb=0;kb<2;kb++){
    bf16x8 a = *(const bf16x8*)&hB[m0+lr][kb*32 + lg*8];
    #pragma unroll
    for (int nt=0;nt<4;nt++){
      bf16x8 b = *(const bf16x8*)&WTr3[(nt*16+lr)*64 + kb*32 + lg*8];
      acc[nt] = __builtin_amdgcn_mfma_f32_16x16x32_bf16(a, b, acc[nt], 0,0,0);
    }
  }
  #pragma unroll
  for (int nt=0;nt<4;nt++)
    #pragma unroll
    for (int r=0;r<4;r++)
      hA[m0+lg*4+r][nt*16+lr] = f2b(silu_f(acc[nt][r]));
  // ---- layer4 (no activation), N=512 in 8 chunks of 64, wave-private restage ----
  int li0 = i0 - ebase + m0;
  for (int g=0; g<8; g++){
    f32x4 a4[4];
    #pragma unroll
    for (int nt=0;nt<4;nt++) a4[nt]=(f32x4)(0.f);
    for (int kb=0;kb<2;kb++){
      bf16x8 a = *(const bf16x8*)&hA[m0+lr][kb*32 + lg*8];
      #pragma unroll
      for (int nt=0;nt<4;nt++){
        bf16x8 b = *(const bf16x8*)&WTr4[(g*64+nt*16+lr)*64 + kb*32 + lg*8];
        a4[nt] = __builtin_amdgcn_mfma_f32_16x16x32_bf16(a, b, a4[nt], 0,0,0);
      }
    }
    #pragma unroll
    for (int nt=0;nt<4;nt++)
      #pragma unroll
      for (int r=0;r<4;r++)
        hB[m0+lg*4+r][nt*16+lr] = f2b(a4[nt][r]);
    {
      int row = l>>2, seg = l&3;
      if (m0 + row < nrows){
        const uint4* srcp = (const uint4*)&hB[m0+row][seg*16];
        uint4 v0 = srcp[0], v1 = srcp[1];
        uint4* dst = (uint4*)&tpw[((size_t)(li0+row)*8 + g)*64 + seg*16];
        dst[0]=v0; dst[1]=v1;
      }
    }
  }
}

// ---------------- K3: CSR gather (no atomics) -> bf16 messages ----------------
__global__ __launch_bounds__(256) void k_gather(
    const unsigned short* __restrict__ tpw, const float4* __restrict__ ybuf,
    const int* __restrict__ sndbuf, const float* __restrict__ densbuf,
    const unsigned short* __restrict__ up_s, const unsigned short* __restrict__ up_v,
    const int* __restrict__ offsets, int nstart,
    unsigned short* __restrict__ msg_s16, unsigned short* __restrict__ msg_v16,
    float* __restrict__ density){
  int w = threadIdx.x>>6, l = threadIdx.x&63;
  int n = nstart + blockIdx.x*4 + w;
  if (n >= NN) return;
  int ebase = offsets[nstart];
  int s0 = offsets[n], s1 = offsets[n+1];
  float mA0=0,mA1=0,mD0=0,mD1=0;
  float mB00=0,mB01=0,mB10=0,mB11=0,mB20=0,mB21=0;
  float mC00=0,mC01=0,mC10=0,mC11=0,mC20=0,mC21=0;
  float dsum=0;
  #pragma unroll 2
  for (int i=s0;i<s1;++i){
    int li = i - ebase;
    int sn = sndbuf[li];
    float4 y = ybuf[li];
    dsum += densbuf[li];
    const unsigned short* tp = tpw + (size_t)li*512;
    float wA0=b2f(tp[l]),     wA1=b2f(tp[64+l]);
    float wB0=b2f(tp[128+l]), wB1=b2f(tp[192+l]);
    float wC0=b2f(tp[256+l]), wC1=b2f(tp[320+l]);
    float wD0=b2f(tp[384+l]), wD1=b2f(tp[448+l]);
    const unsigned short* us = up_s + (size_t)sn*128;
    float xs0=b2f(us[l]), xs1=b2f(us[64+l]);
    const unsigned short* uv = up_v + (size_t)sn*384;
    float xv00=b2f(uv[l]),     xv01=b2f(uv[64+l]);
    float xv10=b2f(uv[128+l]), xv11=b2f(uv[192+l]);
    float xv20=b2f(uv[256+l]), xv21=b2f(uv[320+l]);
    mA0 += wA0*xs0*y.x; mA1 += wA1*xs1*y.x;
    float dot0 = xv00*y.y + xv10*y.z + xv20*y.w;
    float dot1 = xv01*y.y + xv11*y.z + xv21*y.w;
    mD0 += wD0*dot0; mD1 += wD1*dot1;
    float b0 = wB0*xs0, b1 = wB1*xs1;
    mB00 += b0*y.y; mB01 += b1*y.y;
    mB10 += b0*y.z; mB11 += b1*y.z;
    mB20 += b0*y.w; mB21 += b1*y.w;
    float c0 = wC0*y.x, c1 = wC1*y.x;
    mC00 += c0*xv00; mC01 += c1*xv01;
    mC10 += c0*xv10; mC11 += c1*xv11;
    mC20 += c0*xv20; mC21 += c1*xv21;
  }
  unsigned short* ms = msg_s16 + (size_t)n*256;
  ms[l]=f2b(mA0); ms[64+l]=f2b(mA1);
  ms[128+l]=f2b(mD0*INV_SQRT3); ms[192+l]=f2b(mD1*INV_SQRT3);
  unsigned short* mv = msg_v16 + (size_t)n*768;
  mv[l]=f2b(mB00);     mv[64+l]=f2b(mB01);  mv[128+l]=f2b(mC00); mv[192+l]=f2b(mC01);
  mv[256+l]=f2b(mB10); mv[320+l]=f2b(mB11); mv[384+l]=f2b(mC10); mv[448+l]=f2b(mC11);
  mv[512+l]=f2b(mB20); mv[576+l]=f2b(mB21); mv[640+l]=f2b(mC20); mv[704+l]=f2b(mC21);
  if (l==0) density[n]=dsum;
}

// ---------------- K4a: lin1 for all 5 N=128 chunks. grid (NB64, 5) ----------------
// y=0: scal (silu), y=1: gate (sigmoid), y=2..4: vector plane i=y-2 (no gate yet)
__global__ __launch_bounds__(256) void k_post1(
    const unsigned short* __restrict__ msg_s16, const unsigned short* __restrict__ msg_v16,
    const float* __restrict__ density,
    const float* __restrict__ res_s, const float* __restrict__ res_v,
    const unsigned short* __restrict__ Wl10T, const unsigned short* __restrict__ Wl11T,
    const float* __restrict__ alphap, const float* __restrict__ betap,
    unsigned short* __restrict__ scal16, unsigned short* __restrict__ gate16,
    unsigned short* __restrict__ vtmp16){
  __shared__ unsigned short sm[64][264];
  __shared__ float sden[64];
  int nb = blockIdx.x*64, y = blockIdx.y;
  int tid = threadIdx.x;
  int w = tid>>6, l = tid&63, m0 = w*16, lr = l&15, lg = l>>4;
  for (int idx=tid; idx<64*32; idx+=256){
    int row = idx>>5, s8 = idx&31;
    int n = min(nb+row, NN-1);
    const unsigned short* src = (y<2)? &msg_s16[(size_t)n*256 + s8*8]
                                     : &msg_v16[(size_t)n*768 + (y-2)*256 + s8*8];
    *(uint4*)&sm[row][s8*8] = *(const uint4*)src;
  }
  if (tid < 64){
    int n = min(nb+tid, NN-1);
    sden[tid] = density[n]*betap[0] + alphap[0]*20.0f;
  }
  __syncthreads();
  const unsigned short* BT = (y<2)? (Wl10T + (size_t)y*128*256) : Wl11T;
  f32x4 acc[8];
  #pragma unroll
  for (int t=0;t<8;t++) acc[t]=(f32x4)(0.f);
  for (int kb=0;kb<8;kb++){
    bf16x8 a = *(const bf16x8*)&sm[m0+lr][kb*32 + lg*8];
    #pragma unroll
    for (int t=0;t<8;t++){
      bf16x8 b = *(const bf16x8*)&BT[(size_t)(t*16+lr)*256 + kb*32 + lg*8];
      acc[t] = __builtin_amdgcn_mfma_f32_16x16x32_bf16(a, b, acc[t], 0,0,0);
    }
  }
  #pragma unroll
  for (int t=0;t<8;t++){
    #pragma unroll
    for (int r=0;r<4;r++){
      int col = t*16+lr;
      int row = m0 + lg*4 + r;
      int n = nb + row;
      if (n < NN){
        float v = acc[t][r]/sden[row];
        if (y==0){
          v += res_s[(size_t)n*256 + col];
          scal16[(size_t)n*128 + col] = f2b(silu_f(v));
        } else if (y==1){
          v += res_s[(size_t)n*256 + 128 + col];
          gate16[(size_t)n*128 + col] = f2b(sigmoid_f(v));
        } else {
          int i = y-2;
          v += res_v[((size_t)n*3+i)*128 + col];
          vtmp16[((size_t)i*NN + n)*128 + col] = f2b(v);
        }
      }
    }
  }
}

// ---------------- K4b: lin2 for 4 output components. grid (NB64, 4) ----------------
// y=0: scal@Wl20 -> comp0; y=1..3: (vtmp_i * gate)@Wl21 -> comp y
__global__ __launch_bounds__(256) void k_post2(
    const unsigned short* __restrict__ scal16, const unsigned short* __restrict__ gate16,
    const unsigned short* __restrict__ vtmp16,
    const unsigned short* __restrict__ Wl20T, const unsigned short* __restrict__ Wl21T,
    float* __restrict__ out_msg){
  __shared__ unsigned short sA[64][136];
  int nb = blockIdx.x*64, y = blockIdx.y;
  int tid = threadIdx.x;
  int w = tid>>6, l = tid&63, m0 = w*16, lr = l&15, lg = l>>4;
  for (int idx=tid; idx<64*16; idx+=256){
    int row = idx>>4, s8 = idx&15;
    int n = min(nb+row, NN-1);
    if (y==0){
      *(uint4*)&sA[row][s8*8] = *(const uint4*)&scal16[(size_t)n*128 + s8*8];
    } else {
      int i = y-1;
      uint4 va = *(const uint4*)&vtmp16[((size_t)i*NN + n)*128 + s8*8];
      uint4 vg = *(const uint4*)&gate16[(size_t)n*128 + s8*8];
      const unsigned short* pa = (const unsigned short*)&va;
      const unsigned short* pg = (const unsigned short*)&vg;
      unsigned short o[8];
      #pragma unroll
      for (int j=0;j<8;j++) o[j] = f2b(b2f(pa[j])*b2f(pg[j]));
      *(uint4*)&sA[row][s8*8] = *(const uint4*)o;
    }
  }
  __syncthreads();
  const unsigned short* BT = (y==0)? Wl20T : Wl21T;
  f32x4 acc[8];
  #pragma unroll
  for (int t=0;t<8;t++) acc[t]=(f32x4)(0.f);
  #pragma unroll
  for (int kb=0;kb<4;kb++){
    bf16x8 a = *(const bf16x8*)&sA[m0+lr][kb*32 + lg*8];
    #pragma unroll
    for (int t=0;t<8;t++){
      bf16x8 b = *(const bf16x8*)&BT[(size_t)(t*16+lr)*128 + kb*32 + lg*8];
      acc[t] = __builtin_amdgcn_mfma_f32_16x16x32_bf16(a, b, acc[t], 0,0,0);
    }
  }
  #pragma unroll
  for (int t=0;t<8;t++){
    #pragma unroll
    for (int r=0;r<4;r++){
      int col = t*16+lr;
      int n = nb + m0 + lg*4 + r;
      if (n < NN) out_msg[(size_t)n*512 + col*4 + y] = acc[t][r];
    }
  }
}

extern "C" void kernel_launch(void* const* d_in, const int* in_sizes, int n_in,
                              void* d_out, int out_size, void* d_ws, size_t ws_size,
                              hipStream_t stream){
  (void)in_sizes; (void)n_in; (void)out_size; (void)ws_size;
  const float* attrs = (const float*)d_in[0];
  const float* feats = (const float*)d_in[1];
  const float* ea    = (const float*)d_in[2];
  const float* ef    = (const float*)d_in[3];
  const float* Wsrc  = (const float*)d_in[4];
  const float* Wtgt  = (const float*)d_in[5];
  const float* Wup0  = (const float*)d_in[6];
  const float* Wup1  = (const float*)d_in[7];
  const float* Wsk0  = (const float*)d_in[8];
  const float* Wsk1  = (const float*)d_in[9];
  const float* Wres0 = (const float*)d_in[10];
  const float* Wres1 = (const float*)d_in[11];
  const float* Wl10  = (const float*)d_in[12];
  const float* Wl11  = (const float*)d_in[13];
  const float* Wl20  = (const float*)d_in[14];
  const float* Wl21  = (const float*)d_in[15];
  const float* Wr1   = (const float*)d_in[16];
  const float* Wr2   = (const float*)d_in[17];
  const float* Wr3   = (const float*)d_in[18];
  const float* Wr4   = (const float*)d_in[19];
  const float* Wd1   = (const float*)d_in[20];
  const float* Wd2   = (const float*)d_in[21];
  const float* alphap= (const float*)d_in[22];
  const float* betap = (const float*)d_in[23];
  const int*   eidx  = (const int*)d_in[24];

  char* p = (char*)d_ws;
  auto alloc = [&](size_t bytes)->char*{ char* r=p; p += (bytes+255)&~(size_t)255; return r; };
  unsigned short* tpw  = (unsigned short*)alloc((size_t)CAP*512*2);
  unsigned short* msg_s16 = (unsigned short*)alloc((size_t)NN*256*2);
  unsigned short* msg_v16 = (unsigned short*)alloc((size_t)NN*768*2);
  float*  res_s   = (float*)alloc((size_t)NN*256*4);
  float*  res_v   = (float*)alloc((size_t)NN*384*4);
  float*  density = (float*)alloc((size_t)NN*4);
  float4* ybuf    = (float4*)alloc((size_t)CAP*16);
  float*  densbuf = (float*)alloc((size_t)CAP*4);
  int*    sndbuf  = (int*)alloc((size_t)CAP*4);
  unsigned short* se16 = (unsigned short*)alloc((size_t)NN*128*2);
  unsigned short* te16 = (unsigned short*)alloc((size_t)NN*128*2);
  unsigned short* up_s16 = (unsigned short*)alloc((size_t)NN*128*2);
  unsigned short* up_v16 = (unsigned short*)alloc((size_t)NN*384*2);
  unsigned short* fs16 = (unsigned short*)alloc((size_t)NN*128*2);
  unsigned short* fv16 = (unsigned short*)alloc((size_t)NN*384*2);
  unsigned short* WTr1 = (unsigned short*)alloc(18432*2);
  unsigned short* WTd1 = (unsigned short*)alloc(18432*2);
  unsigned short* WTr2 = (unsigned short*)alloc(4096*2);
  unsigned short* WTr3 = (unsigned short*)alloc(4096*2);
  unsigned short* WTr4 = (unsigned short*)alloc(32768*2);
  unsigned short* Wl10T = (unsigned short*)alloc(65536*2);
  unsigned short* Wl11T = (unsigned short*)alloc(32768*2);
  unsigned short* Wl20T = (unsigned short*)alloc(16384*2);
  unsigned short* Wl21T = (unsigned short*)alloc(16384*2);
  unsigned short* WnsT  = (unsigned short*)alloc(65536*2);
  unsigned short* WnvT  = (unsigned short*)alloc(49152*2);
  int* deg     = (int*)alloc(10240*4);
  int* cursor  = (int*)alloc(10240*4);
  int* offsets = (int*)alloc(10256*4);
  int* elist   = (int*)alloc((size_t)NE*4);

  // dead-buffer aliasing for the post-path intermediates:
  unsigned short* scal16 = fs16;   // NN*128, fs16 dead after k_node_pre2
  unsigned short* vtmp16 = fv16;   // 3*NN*128, fv16 dead after k_node_pre2
  unsigned short* gate16 = se16;   // NN*128, se16 dead after k_tpw chunks

  float* out_msg = (float*)d_out;               // NN*512
  float* out_sc  = out_msg + (size_t)NN*512;    // NN*512

  hipMemsetAsync(deg, 0, 2*10240*sizeof(int), stream);

  k_prep<<<1264, 256, 0, stream>>>(Wr1, Wd1, Wr2, Wr3, Wr4,
                                   Wl10, Wl11, Wl20, Wl21,
                                   Wsk0, Wup0, Wres0, Wsk1, Wup1, Wres1,
                                   WTr1, WTd1, WTr2, WTr3, WTr4,
                                   Wl10T, Wl11T, Wl20T, Wl21T, WnsT, WnvT);
  k_emb<<<(NN*MUL+255)/256, 256, 0, stream>>>(attrs, Wsrc, Wtgt, se16, te16);
  k_feat_prep<<<NN*512/256, 256, 0, stream>>>(feats, fs16, fv16);
  k_node_pre2<<<dim3(NB64,13), 256, 0, stream>>>(fs16, fv16, WnsT, WnvT,
                                                 out_sc, up_s16, up_v16, res_s, res_v);
  k_deg<<<(NE+255)/256, 256, 0, stream>>>(eidx, deg);
  k_scan<<<1, 256, 0, stream>>>(deg, offsets);
  k_fill<<<(NE+255)/256, 256, 0, stream>>>(eidx, offsets, cursor, elist);

  for (int c=0; c<NCHUNK; ++c){
    k_tpw<<<CAP/64, 256, 0, stream>>>(elist, eidx, ef, ea, se16, te16,
                                      WTr1, WTd1, WTr2, WTr3, WTr4, Wd2,
                                      offsets, c*NPC, (c+1)*NPC,
                                      tpw, ybuf, sndbuf, densbuf);
    k_gather<<<NPC/4, 256, 0, stream>>>(tpw, ybuf, sndbuf, densbuf, up_s16, up_v16,
                                        offsets, c*NPC, msg_s16, msg_v16, density);
  }

  k_post1<<<dim3(NB64,5), 256, 0, stream>>>(msg_s16, msg_v16, density, res_s, res_v,
                                            Wl10T, Wl11T, alphap, betap,
                                            scal16, gate16, vtmp16);
  k_post2<<<dim3(NB64,4), 256, 0, stream>>>(scal16, gate16, vtmp16,
                                            Wl20T, Wl21T, out_msg);
}

// Round 5
// 557.393 us; speedup vs baseline: 1.4134x; 1.2288x over previous
//
#include <hip/hip_runtime.h>
#include <math.h>

#define NN 10000
#define NE 160000
#define MUL 128
#define ADIM 10
#define RADF 8
#define HID 64
#define INV_SQRT3 0.57735026918962576f
#define NCHUNK 4
#define NPC 2500           // nodes per chunk
#define CAP 44032          // max edges per chunk buffer
#define NB64 157           // ceil(NN/64)

typedef __attribute__((ext_vector_type(8))) short bf16x8;
typedef __attribute__((ext_vector_type(4))) float f32x4;

__device__ __forceinline__ float silu_f(float x){ return x / (1.0f + __expf(-x)); }
__device__ __forceinline__ float sigmoid_f(float x){ return 1.0f / (1.0f + __expf(-x)); }
__device__ __forceinline__ unsigned short f2b(float f){
  union{float f; unsigned u;} v; v.f=f;
  unsigned r = (v.u + 0x7fffu + ((v.u>>16)&1u))>>16;
  return (unsigned short)r;
}
__device__ __forceinline__ float b2f(unsigned short h){
  union{unsigned u; float f;} v; v.u = ((unsigned)h)<<16; return v.f;
}
__device__ __forceinline__ float b2f_lo(unsigned u){
  union{unsigned u; float f;} v; v.u = u<<16; return v.f;
}
__device__ __forceinline__ float b2f_hi(unsigned u){
  union{unsigned u; float f;} v; v.u = u & 0xffff0000u; return v.f;
}

// ---------------- weight combine: Wc[m][10][64], m=0..3 ----------------
// m0: Wsrc@Wr1[8:136], m1: Wtgt@Wr1[136:264], m2: Wsrc@Wd1[8:136], m3: Wtgt@Wd1[136:264]
__global__ __launch_bounds__(256) void k_wcomb(
    const float* __restrict__ Wsrc, const float* __restrict__ Wtgt,
    const float* __restrict__ Wr1, const float* __restrict__ Wd1,
    float* __restrict__ Wc){
  int tid = threadIdx.x;
  int m = tid>>6, c = tid&63;
  const float* WA = (m&1)? Wtgt : Wsrc;
  const float* WB = (m<2)? Wr1 : Wd1;
  int koff = (m&1)? 136 : 8;
  for (int a=0;a<ADIM;a++){
    float s=0.f;
    for (int k=0;k<128;k++) s += WA[a*128+k]*WB[(koff+k)*64+c];
    Wc[(m*ADIM+a)*64+c] = s;
  }
}

// ---------------- per-node layer1 partials (f32) ----------------
__global__ __launch_bounds__(256) void k_nodeemb(
    const float* __restrict__ attrs, const float* __restrict__ Wc,
    float* __restrict__ srP, float* __restrict__ trP,
    float* __restrict__ sdP, float* __restrict__ tdP){
  int idx = blockIdx.x*256 + threadIdx.x;
  if (idx >= NN*64) return;
  int n = idx>>6, c = idx&63;
  float s0=0,s1=0,s2=0,s3=0;
  #pragma unroll
  for (int a=0;a<ADIM;a++){
    float x = attrs[n*ADIM+a];
    s0 += x*Wc[(0*ADIM+a)*64+c];
    s1 += x*Wc[(1*ADIM+a)*64+c];
    s2 += x*Wc[(2*ADIM+a)*64+c];
    s3 += x*Wc[(3*ADIM+a)*64+c];
  }
  srP[idx]=s0; trP[idx]=s1; sdP[idx]=s2; tdP[idx]=s3;
}

// ---------------- feat prep: split feats into contiguous bf16 s / v_i ----------------
__global__ __launch_bounds__(256) void k_feat_prep(
    const float* __restrict__ feats, unsigned short* __restrict__ fs16,
    unsigned short* __restrict__ fv16){
  int idx = blockIdx.x*256 + threadIdx.x;   // over NN*512
  int n = idx >> 9, c = idx & 511;
  float v = feats[idx];
  if (c < 128) fs16[n*128 + c] = f2b(v);
  else {
    int q = c - 128; int u = q/3; int i = q - 3*u;
    fv16[((size_t)n*3 + i)*128 + u] = f2b(v);
  }
}

// ---------------- weight prep: transpose + bf16 cast ----------------
__global__ __launch_bounds__(256) void k_prep(
    const float* __restrict__ Wr2, const float* __restrict__ Wr3,
    const float* __restrict__ Wr4,
    const float* __restrict__ Wl10, const float* __restrict__ Wl11,
    const float* __restrict__ Wl20, const float* __restrict__ Wl21,
    const float* __restrict__ Wsk0, const float* __restrict__ Wup0, const float* __restrict__ Wres0,
    const float* __restrict__ Wsk1, const float* __restrict__ Wup1, const float* __restrict__ Wres1,
    unsigned short* __restrict__ WTr2, unsigned short* __restrict__ WTr3,
    unsigned short* __restrict__ WTr4,
    unsigned short* __restrict__ Wl10T, unsigned short* __restrict__ Wl11T,
    unsigned short* __restrict__ Wl20T, unsigned short* __restrict__ Wl21T,
    unsigned short* __restrict__ WnsT, unsigned short* __restrict__ WnvT){
  int idx = blockIdx.x*256 + threadIdx.x;
  if (idx < 4096){
    int j = idx; int n=j>>6, k=j&63;
    WTr2[j] = f2b(Wr2[k*64+n]);
  } else if (idx < 8192){
    int j = idx-4096; int n=j>>6, k=j&63;
    WTr3[j] = f2b(Wr3[k*64+n]);
  } else if (idx < 40960){
    int j = idx-8192; int n=j>>6, k=j&63;
    WTr4[j] = f2b(Wr4[k*512+n]);
  } else if (idx < 106496){
    int j = idx-40960; int n=j>>8, k=j&255;
    Wl10T[j] = f2b(Wl10[k*256+n]);
  } else if (idx < 139264){
    int j = idx-106496; int n=j>>8, k=j&255;
    Wl11T[j] = f2b(Wl11[k*128+n]);
  } else if (idx < 155648){
    int j = idx-139264; int n=j>>7, k=j&127;
    Wl20T[j] = f2b(Wl20[k*128+n]);
  } else if (idx < 172032){
    int j = idx-155648; int n=j>>7, k=j&127;
    Wl21T[j] = f2b(Wl21[k*128+n]);
  } else if (idx < 237568){
    int j = idx-172032; int n=j>>7, k=j&127;
    float v;
    if (n < 128)      v = Wsk0[k*128+n];
    else if (n < 256) v = Wup0[k*128+(n-128)];
    else              v = Wres0[k*256+(n-256)];
    WnsT[j] = f2b(v);
  } else if (idx < 286720){
    int j = idx-237568; int n=j>>7, k=j&127;
    float v;
    if (n < 128)      v = Wsk1[k*128+n];
    else if (n < 256) v = Wup1[k*128+(n-128)];
    else              v = Wres1[k*128+(n-256)];
    WnvT[j] = f2b(v);
  }
}

// ---------------- K1: per-node precompute (skip/up/res) via MFMA ----------------
// grid (NB64, 13): blockIdx.y -> (g, ntc) chunk. g=0: 4 chunks; g=1..3: 3 each.
// up outputs written PACKED: word l = (col l, col 64+l) bf16 pair.
__global__ __launch_bounds__(256) void k_node_pre2(
    const unsigned short* __restrict__ fs16, const unsigned short* __restrict__ fv16,
    const unsigned short* __restrict__ WnsT, const unsigned short* __restrict__ WnvT,
    float* __restrict__ out_sc,
    unsigned* __restrict__ up_sp, unsigned* __restrict__ up_vp,
    float* __restrict__ res_s, float* __restrict__ res_v){
  __shared__ unsigned short fA[64][136];
  int nb = blockIdx.x*64;
  int c = blockIdx.y;
  int g, ntc;
  if (c < 4){ g=0; ntc=c; } else { g = 1 + (c-4)/3; ntc = (c-4)%3; }
  int tid = threadIdx.x;
  int w = tid>>6, l = tid&63, m0 = w*16, lr = l&15, lg = l>>4;
  for (int idx=tid; idx<64*16; idx+=256){
    int row = idx>>4, s8 = idx&15;
    int n = min(nb+row, NN-1);
    const unsigned short* src = (g==0) ? &fs16[(size_t)n*128 + s8*8]
                                       : &fv16[((size_t)n*3 + (g-1))*128 + s8*8];
    *(uint4*)&fA[row][s8*8] = *(const uint4*)src;
  }
  __syncthreads();
  const unsigned short* WT = ((g==0)? WnsT : WnvT) + (size_t)ntc*128*128;
  f32x4 acc[8];
  #pragma unroll
  for (int t=0;t<8;t++) acc[t]=(f32x4)(0.f);
  #pragma unroll
  for (int kb=0;kb<4;kb++){
    bf16x8 a = *(const bf16x8*)&fA[m0+lr][kb*32 + lg*8];
    #pragma unroll
    for (int t=0;t<8;t++){
      bf16x8 b = *(const bf16x8*)&WT[(size_t)(t*16+lr)*128 + kb*32 + lg*8];
      acc[t] = __builtin_amdgcn_mfma_f32_16x16x32_bf16(a, b, acc[t], 0,0,0);
    }
  }
  #pragma unroll
  for (int t=0;t<8;t++){
    #pragma unroll
    for (int r=0;r<4;r++){
      int col = (ntc*8+t)*16 + lr;
      int row = m0 + lg*4 + r;
      int n = nb + row;
      if (n < NN){
        float v = acc[t][r];
        if (g==0){
          if (col < 128)      out_sc[(size_t)n*512 + col] = v;
          else if (col < 256){
            int cc = col-128;
            ((unsigned short*)up_sp)[((size_t)n*64 + (cc&63))*2 + (cc>>6)] = f2b(v);
          } else              res_s[(size_t)n*256 + col-256] = v;
        } else {
          int i = g-1;
          if (col < 128)      out_sc[(size_t)n*512 + 128 + col*3 + i] = v;
          else if (col < 256){
            int cc = col-128;
            ((unsigned short*)up_vp)[(((size_t)n*3+i)*64 + (cc&63))*2 + (cc>>6)] = f2b(v);
          } else              res_v[((size_t)n*3+i)*128 + col-256] = v;
        }
      }
    }
  }
}

// ---------------- CSR build ----------------
__global__ __launch_bounds__(256) void k_deg(const int* __restrict__ eidx, int* __restrict__ deg){
  int i = blockIdx.x*256+threadIdx.x;
  if (i<NE) atomicAdd(&deg[eidx[2*i+1]],1);
}
__global__ __launch_bounds__(256) void k_scan(const int* __restrict__ deg, int* __restrict__ offsets){
  __shared__ int part[256];
  int t = threadIdx.x; int base = t*40;
  int s=0;
  for (int k=0;k<40;k++){ int idx=base+k; if (idx<NN) s+=deg[idx]; }
  part[t]=s; __syncthreads();
  if (t==0){ int run=0; for (int i=0;i<256;i++){ int v=part[i]; part[i]=run; run+=v; } }
  __syncthreads();
  int run = part[t];
  for (int k=0;k<40;k++){
    int idx=base+k;
    if (idx<=NN) offsets[idx]=run;
    if (idx<NN) run+=deg[idx];
  }
}
__global__ __launch_bounds__(256) void k_fill(const int* __restrict__ eidx, const int* __restrict__ offsets,
                                              int* __restrict__ cursor, int* __restrict__ elist){
  int i = blockIdx.x*256+threadIdx.x;
  if (i<NE){ int r = eidx[2*i+1]; int p = atomicAdd(&cursor[r],1); elist[offsets[r]+p]=i; }
}

// ---------------- K2: edge MLP (layer1 folded to per-node partials) ----------------
// outputs tpwp PACKED u32: [edge][4 grps][64 words], word l of grp G = (col G*128+l, col G*128+64+l)
__global__ __launch_bounds__(256) void k_tpw(
    const int* __restrict__ elist, const int* __restrict__ eidx,
    const float* __restrict__ ef, const float* __restrict__ ea,
    const float* __restrict__ srP, const float* __restrict__ trP,
    const float* __restrict__ sdP, const float* __restrict__ tdP,
    const float* __restrict__ Wr1, const float* __restrict__ Wd1, const float* __restrict__ Wd2,
    const unsigned short* __restrict__ WTr2, const unsigned short* __restrict__ WTr3,
    const unsigned short* __restrict__ WTr4,
    const int* __restrict__ offsets, int nstart, int nend,
    unsigned* __restrict__ tpwp, float4* __restrict__ ybuf,
    int* __restrict__ sndbuf, float* __restrict__ densbuf){
  __shared__ unsigned short hA[64][72];
  __shared__ unsigned short hB[64][72];
  __shared__ unsigned short hC[64][72];
  __shared__ float efs[64][8];
  __shared__ int s_snd[64], s_rcv[64];
  int ebase = offsets[nstart];
  int eend  = min(offsets[nend], ebase + CAP);
  int i0 = ebase + blockIdx.x*64;
  if (i0 >= eend) return;
  int nrows = min(64, eend - i0);
  int tid = threadIdx.x;
  int w = tid>>6, l = tid&63, m0 = w*16, lr = l&15, lg = l>>4;
  if (tid < 64){
    int ii = min(i0 + tid, eend-1);
    int e = elist[ii];
    int sn = eidx[2*e], rc = eidx[2*e+1];
    s_snd[tid]=sn; s_rcv[tid]=rc;
    if (tid < nrows){
      int li = i0 - ebase + tid;
      sndbuf[li] = sn;
      ybuf[li] = ((const float4*)ea)[e];
    }
  }
  if (tid < 128){
    int r = tid>>1, hf = tid&1;
    int e = elist[min(i0+r, eend-1)];
    *(float4*)&efs[r][hf*4] = *(const float4*)&ef[(size_t)e*8 + hf*4];
  }
  __syncthreads();
  // ---- layer1 (VALU, f32): h1 = ef@Wr1[0:8] + srP[sn] + trP[rc]; den likewise ----
  {
    float wr[8], wd[8];
    #pragma unroll
    for (int k=0;k<8;k++){ wr[k]=Wr1[k*64+l]; wd[k]=Wd1[k*64+l]; }
    float wd2c = Wd2[l];
    #pragma unroll
    for (int j=0;j<16;j++){
      int r = m0+j;
      int sn = s_snd[r], rc = s_rcv[r];
      float h  = srP[sn*64+l] + trP[rc*64+l];
      float hd = sdP[sn*64+l] + tdP[rc*64+l];
      #pragma unroll
      for (int k=0;k<8;k++){ float ek=efs[r][k]; h += ek*wr[k]; hd += ek*wd[k]; }
      hA[r][l] = f2b(silu_f(h));
      float sv = silu_f(hd)*wd2c;
      #pragma unroll
      for (int m=32;m;m>>=1) sv += __shfl_xor(sv, m);
      if (l==0 && j+m0 < nrows) densbuf[i0 - ebase + r] = tanhf(sv*sv);
    }
  }
  // ---- layer2: hA -> hB (wave-private rows, no barrier) ----
  f32x4 acc[4];
  #pragma unroll
  for (int nt=0;nt<4;nt++) acc[nt]=(f32x4)(0.f);
  for (int kb=0;kb<2;kb++){
    bf16x8 a = *(const bf16x8*)&hA[m0+lr][kb*32 + lg*8];
    #pragma unroll
    for (int nt=0;nt<4;nt++){
      bf16x8 b = *(const bf16x8*)&WTr2[(nt*16+lr)*64 + kb*32 + lg*8];
      acc[nt] = __builtin_amdgcn_mfma_f32_16x16x32_bf16(a, b, acc[nt], 0,0,0);
    }
  }
  #pragma unroll
  for (int nt=0;nt<4;nt++)
    #pragma unroll
    for (int r=0;r<4;r++)
      hB[m0+lg*4+r][nt*16+lr] = f2b(silu_f(acc[nt][r]));
  // ---- layer3: hB -> hA ----
  #pragma unroll
  for (int nt=0;nt<4;nt++) acc[nt]=(f32x4)(0.f);
  for (int kb=0;kb<2;kb++){
    bf16x8 a = *(const bf16x8*)&hB[m0+lr][kb*32 + lg*8];
    #pragma unroll
    for (int nt=0;nt<4;nt++){
      bf16x8 b = *(const bf16x8*)&WTr3[(nt*16+lr)*64 + kb*32 + lg*8];
      acc[nt] = __builtin_amdgcn_mfma_f32_16x16x32_bf16(a, b, acc[nt], 0,0,0);
    }
  }
  #pragma unroll
  for (int nt=0;nt<4;nt++)
    #pragma unroll
    for (int r=0;r<4;r++)
      hA[m0+lg*4+r][nt*16+lr] = f2b(silu_f(acc[nt][r]));
  // ---- layer4: hA -> (hB even chunk, hC odd chunk) -> packed u32 store ----
  for (int G=0; G<4; G++){
    f32x4 aE[4], aO[4];
    #pragma unroll
    for (int nt=0;nt<4;nt++){ aE[nt]=(f32x4)(0.f); aO[nt]=(f32x4)(0.f); }
    for (int kb=0;kb<2;kb++){
      bf16x8 a = *(const bf16x8*)&hA[m0+lr][kb*32 + lg*8];
      #pragma unroll
      for (int nt=0;nt<4;nt++){
        bf16x8 bE = *(const bf16x8*)&WTr4[((2*G)*64+nt*16+lr)*64 + kb*32 + lg*8];
        bf16x8 bO = *(const bf16x8*)&WTr4[((2*G+1)*64+nt*16+lr)*64 + kb*32 + lg*8];
        aE[nt] = __builtin_amdgcn_mfma_f32_16x16x32_bf16(a, bE, aE[nt], 0,0,0);
        aO[nt] = __builtin_amdgcn_mfma_f32_16x16x32_bf16(a, bO, aO[nt], 0,0,0);
      }
    }
    #pragma unroll
    for (int nt=0;nt<4;nt++)
      #pragma unroll
      for (int r=0;r<4;r++){
        hB[m0+lg*4+r][nt*16+lr] = f2b(aE[nt][r]);
        hC[m0+lg*4+r][nt*16+lr] = f2b(aO[nt][r]);
      }
    {
      int row = m0 + (l>>2), seg = l&3;
      if (row < nrows){
        const unsigned short* pb = &hB[row][seg*16];
        const unsigned short* pc = &hC[row][seg*16];
        unsigned o[16];
        #pragma unroll
        for (int t=0;t<16;t++) o[t] = (unsigned)pb[t] | ((unsigned)pc[t]<<16);
        size_t base = (size_t)(i0 - ebase + row)*256 + G*64 + seg*16;
        *(uint4*)&tpwp[base+0]  = *(uint4*)&o[0];
        *(uint4*)&tpwp[base+4]  = *(uint4*)&o[4];
        *(uint4*)&tpwp[base+8]  = *(uint4*)&o[8];
        *(uint4*)&tpwp[base+12] = *(uint4*)&o[12];
      }
    }
  }
}

// ---------------- K3: CSR gather (no atomics), packed u32 loads ----------------
__global__ __launch_bounds__(256) void k_gather(
    const unsigned* __restrict__ tpwp, const float4* __restrict__ ybuf,
    const int* __restrict__ sndbuf, const float* __restrict__ densbuf,
    const unsigned* __restrict__ up_sp, const unsigned* __restrict__ up_vp,
    const int* __restrict__ offsets, int nstart,
    unsigned short* __restrict__ msg_s16, unsigned short* __restrict__ msg_v16,
    float* __restrict__ density){
  int w = threadIdx.x>>6, l = threadIdx.x&63;
  int n = nstart + blockIdx.x*4 + w;
  if (n >= NN) return;
  int ebase = offsets[nstart];
  int s0 = offsets[n], s1 = offsets[n+1];
  float mA0=0,mA1=0,mD0=0,mD1=0;
  float mB00=0,mB01=0,mB10=0,mB11=0,mB20=0,mB21=0;
  float mC00=0,mC01=0,mC10=0,mC11=0,mC20=0,mC21=0;
  float dsum=0;
  #pragma unroll 2
  for (int i=s0;i<s1;++i){
    int li = i - ebase;
    int sn = sndbuf[li];
    float4 y = ybuf[li];
    dsum += densbuf[li];
    const unsigned* tp = tpwp + (size_t)li*256;
    unsigned uA = tp[l], uB = tp[64+l], uC = tp[128+l], uD = tp[192+l];
    float wA0=b2f_lo(uA), wA1=b2f_hi(uA);
    float wB0=b2f_lo(uB), wB1=b2f_hi(uB);
    float wC0=b2f_lo(uC), wC1=b2f_hi(uC);
    float wD0=b2f_lo(uD), wD1=b2f_hi(uD);
    unsigned us = up_sp[(size_t)sn*64 + l];
    float xs0=b2f_lo(us), xs1=b2f_hi(us);
    unsigned uv0 = up_vp[((size_t)sn*3+0)*64 + l];
    unsigned uv1 = up_vp[((size_t)sn*3+1)*64 + l];
    unsigned uv2 = up_vp[((size_t)sn*3+2)*64 + l];
    float xv00=b2f_lo(uv0), xv01=b2f_hi(uv0);
    float xv10=b2f_lo(uv1), xv11=b2f_hi(uv1);
    float xv20=b2f_lo(uv2), xv21=b2f_hi(uv2);
    mA0 += wA0*xs0*y.x; mA1 += wA1*xs1*y.x;
    float dot0 = xv00*y.y + xv10*y.z + xv20*y.w;
    float dot1 = xv01*y.y + xv11*y.z + xv21*y.w;
    mD0 += wD0*dot0; mD1 += wD1*dot1;
    float b0 = wB0*xs0, b1 = wB1*xs1;
    mB00 += b0*y.y; mB01 += b1*y.y;
    mB10 += b0*y.z; mB11 += b1*y.z;
    mB20 += b0*y.w; mB21 += b1*y.w;
    float c0 = wC0*y.x, c1 = wC1*y.x;
    mC00 += c0*xv00; mC01 += c1*xv01;
    mC10 += c0*xv10; mC11 += c1*xv11;
    mC20 += c0*xv20; mC21 += c1*xv21;
  }
  unsigned short* ms = msg_s16 + (size_t)n*256;
  ms[l]=f2b(mA0); ms[64+l]=f2b(mA1);
  ms[128+l]=f2b(mD0*INV_SQRT3); ms[192+l]=f2b(mD1*INV_SQRT3);
  unsigned short* mv = msg_v16 + (size_t)n*768;
  mv[l]=f2b(mB00);     mv[64+l]=f2b(mB01);  mv[128+l]=f2b(mC00); mv[192+l]=f2b(mC01);
  mv[256+l]=f2b(mB10); mv[320+l]=f2b(mB11); mv[384+l]=f2b(mC10); mv[448+l]=f2b(mC11);
  mv[512+l]=f2b(mB20); mv[576+l]=f2b(mB21); mv[640+l]=f2b(mC20); mv[704+l]=f2b(mC21);
  if (l==0) density[n]=dsum;
}

// ---------------- K4a: lin1 for all 5 N=128 chunks. grid (NB64, 5) ----------------
__global__ __launch_bounds__(256) void k_post1(
    const unsigned short* __restrict__ msg_s16, const unsigned short* __restrict__ msg_v16,
    const float* __restrict__ density,
    const float* __restrict__ res_s, const float* __restrict__ res_v,
    const unsigned short* __restrict__ Wl10T, const unsigned short* __restrict__ Wl11T,
    const float* __restrict__ alphap, const float* __restrict__ betap,
    unsigned short* __restrict__ scal16, unsigned short* __restrict__ gate16,
    unsigned short* __restrict__ vtmp16){
  __shared__ unsigned short sm[64][264];
  __shared__ float sden[64];
  int nb = blockIdx.x*64, y = blockIdx.y;
  int tid = threadIdx.x;
  int w = tid>>6, l = tid&63, m0 = w*16, lr = l&15, lg = l>>4;
  for (int idx=tid; idx<64*32; idx+=256){
    int row = idx>>5, s8 = idx&31;
    int n = min(nb+row, NN-1);
    const unsigned short* src = (y<2)? &msg_s16[(size_t)n*256 + s8*8]
                                     : &msg_v16[(size_t)n*768 + (y-2)*256 + s8*8];
    *(uint4*)&sm[row][s8*8] = *(const uint4*)src;
  }
  if (tid < 64){
    int n = min(nb+tid, NN-1);
    sden[tid] = density[n]*betap[0] + alphap[0]*20.0f;
  }
  __syncthreads();
  const unsigned short* BT = (y<2)? (Wl10T + (size_t)y*128*256) : Wl11T;
  f32x4 acc[8];
  #pragma unroll
  for (int t=0;t<8;t++) acc[t]=(f32x4)(0.f);
  for (int kb=0;kb<8;kb++){
    bf16x8 a = *(const bf16x8*)&sm[m0+lr][kb*32 + lg*8];
    #pragma unroll
    for (int t=0;t<8;t++){
      bf16x8 b = *(const bf16x8*)&BT[(size_t)(t*16+lr)*256 + kb*32 + lg*8];
      acc[t] = __builtin_amdgcn_mfma_f32_16x16x32_bf16(a, b, acc[t], 0,0,0);
    }
  }
  #pragma unroll
  for (int t=0;t<8;t++){
    #pragma unroll
    for (int r=0;r<4;r++){
      int col = t*16+lr;
      int row = m0 + lg*4 + r;
      int n = nb + row;
      if (n < NN){
        float v = acc[t][r]/sden[row];
        if (y==0){
          v += res_s[(size_t)n*256 + col];
          scal16[(size_t)n*128 + col] = f2b(silu_f(v));
        } else if (y==1){
          v += res_s[(size_t)n*256 + 128 + col];
          gate16[(size_t)n*128 + col] = f2b(sigmoid_f(v));
        } else {
          int i = y-2;
          v += res_v[((size_t)n*3+i)*128 + col];
          vtmp16[((size_t)i*NN + n)*128 + col] = f2b(v);
        }
      }
    }
  }
}

// ---------------- K4b: lin2 for 4 output components. grid (NB64, 4) ----------------
__global__ __launch_bounds__(256) void k_post2(
    const unsigned short* __restrict__ scal16, const unsigned short* __restrict__ gate16,
    const unsigned short* __restrict__ vtmp16,
    const unsigned short* __restrict__ Wl20T, const unsigned short* __restrict__ Wl21T,
    float* __restrict__ out_msg){
  __shared__ unsigned short sA[64][136];
  int nb = blockIdx.x*64, y = blockIdx.y;
  int tid = threadIdx.x;
  int w = tid>>6, l = tid&63, m0 = w*16, lr = l&15, lg = l>>4;
  for (int idx=tid; idx<64*16; idx+=256){
    int row = idx>>4, s8 = idx&15;
    int n = min(nb+row, NN-1);
    if (y==0){
      *(uint4*)&sA[row][s8*8] = *(const uint4*)&scal16[(size_t)n*128 + s8*8];
    } else {
      int i = y-1;
      uint4 va = *(const uint4*)&vtmp16[((size_t)i*NN + n)*128 + s8*8];
      uint4 vg = *(const uint4*)&gate16[(size_t)n*128 + s8*8];
      const unsigned short* pa = (const unsigned short*)&va;
      const unsigned short* pg = (const unsigned short*)&vg;
      unsigned short o[8];
      #pragma unroll
      for (int j=0;j<8;j++) o[j] = f2b(b2f(pa[j])*b2f(pg[j]));
      *(uint4*)&sA[row][s8*8] = *(const uint4*)o;
    }
  }
  __syncthreads();
  const unsigned short* BT = (y==0)? Wl20T : Wl21T;
  f32x4 acc[8];
  #pragma unroll
  for (int t=0;t<8;t++) acc[t]=(f32x4)(0.f);
  #pragma unroll
  for (int kb=0;kb<4;kb++){
    bf16x8 a = *(const bf16x8*)&sA[m0+lr][kb*32 + lg*8];
    #pragma unroll
    for (int t=0;t<8;t++){
      bf16x8 b = *(const bf16x8*)&BT[(size_t)(t*16+lr)*128 + kb*32 + lg*8];
      acc[t] = __builtin_amdgcn_mfma_f32_16x16x32_bf16(a, b, acc[t], 0,0,0);
    }
  }
  #pragma unroll
  for (int t=0;t<8;t++){
    #pragma unroll
    for (int r=0;r<4;r++){
      int col = t*16+lr;
      int n = nb + m0 + lg*4 + r;
      if (n < NN) out_msg[(size_t)n*512 + col*4 + y] = acc[t][r];
    }
  }
}

extern "C" void kernel_launch(void* const* d_in, const int* in_sizes, int n_in,
                              void* d_out, int out_size, void* d_ws, size_t ws_size,
                              hipStream_t stream){
  (void)in_sizes; (void)n_in; (void)out_size; (void)ws_size;
  const float* attrs = (const float*)d_in[0];
  const float* feats = (const float*)d_in[1];
  const float* ea    = (const float*)d_in[2];
  const float* ef    = (const float*)d_in[3];
  const float* Wsrc  = (const float*)d_in[4];
  const float* Wtgt  = (const float*)d_in[5];
  const float* Wup0  = (const float*)d_in[6];
  const float* Wup1  = (const float*)d_in[7];
  const float* Wsk0  = (const float*)d_in[8];
  const float* Wsk1  = (const float*)d_in[9];
  const float* Wres0 = (const float*)d_in[10];
  const float* Wres1 = (const float*)d_in[11];
  const float* Wl10  = (const float*)d_in[12];
  const float* Wl11  = (const float*)d_in[13];
  const float* Wl20  = (const float*)d_in[14];
  const float* Wl21  = (const float*)d_in[15];
  const float* Wr1   = (const float*)d_in[16];
  const float* Wr2   = (const float*)d_in[17];
  const float* Wr3   = (const float*)d_in[18];
  const float* Wr4   = (const float*)d_in[19];
  const float* Wd1   = (const float*)d_in[20];
  const float* Wd2   = (const float*)d_in[21];
  const float* alphap= (const float*)d_in[22];
  const float* betap = (const float*)d_in[23];
  const int*   eidx  = (const int*)d_in[24];

  char* p = (char*)d_ws;
  auto alloc = [&](size_t bytes)->char*{ char* r=p; p += (bytes+255)&~(size_t)255; return r; };
  unsigned* tpwp  = (unsigned*)alloc((size_t)CAP*256*4);
  unsigned short* msg_s16 = (unsigned short*)alloc((size_t)NN*256*2);
  unsigned short* msg_v16 = (unsigned short*)alloc((size_t)NN*768*2);
  float*  res_s   = (float*)alloc((size_t)NN*256*4);
  float*  res_v   = (float*)alloc((size_t)NN*384*4);
  float*  density = (float*)alloc((size_t)NN*4);
  float4* ybuf    = (float4*)alloc((size_t)CAP*16);
  float*  densbuf = (float*)alloc((size_t)CAP*4);
  int*    sndbuf  = (int*)alloc((size_t)CAP*4);
  unsigned* up_sp = (unsigned*)alloc((size_t)NN*64*4);
  unsigned* up_vp = (unsigned*)alloc((size_t)NN*192*4);
  unsigned short* fs16 = (unsigned short*)alloc((size_t)NN*128*2);
  unsigned short* fv16 = (unsigned short*)alloc((size_t)NN*384*2);
  float* srP = (float*)alloc((size_t)NN*64*4);
  float* trP = (float*)alloc((size_t)NN*64*4);
  float* sdP = (float*)alloc((size_t)NN*64*4);
  float* tdP = (float*)alloc((size_t)NN*64*4);
  float* Wc  = (float*)alloc(4*ADIM*64*4);
  unsigned short* gate16 = (unsigned short*)alloc((size_t)NN*128*2);
  unsigned short* WTr2 = (unsigned short*)alloc(4096*2);
  unsigned short* WTr3 = (unsigned short*)alloc(4096*2);
  unsigned short* WTr4 = (unsigned short*)alloc(32768*2);
  unsigned short* Wl10T = (unsigned short*)alloc(65536*2);
  unsigned short* Wl11T = (unsigned short*)alloc(32768*2);
  unsigned short* Wl20T = (unsigned short*)alloc(16384*2);
  unsigned short* Wl21T = (unsigned short*)alloc(16384*2);
  unsigned short* WnsT  = (unsigned short*)alloc(65536*2);
  unsigned short* WnvT  = (unsigned short*)alloc(49152*2);
  int* deg     = (int*)alloc(10240*4);
  int* cursor  = (int*)alloc(10240*4);
  int* offsets = (int*)alloc(10256*4);
  int* elist   = (int*)alloc((size_t)NE*4);

  // dead-buffer aliasing for the post-path intermediates:
  unsigned short* scal16 = fs16;   // NN*128, fs16 dead after k_node_pre2
  unsigned short* vtmp16 = fv16;   // 3*NN*128, fv16 dead after k_node_pre2

  float* out_msg = (float*)d_out;               // NN*512
  float* out_sc  = out_msg + (size_t)NN*512;    // NN*512

  hipMemsetAsync(deg, 0, 2*10240*sizeof(int), stream);

  k_wcomb<<<1, 256, 0, stream>>>(Wsrc, Wtgt, Wr1, Wd1, Wc);
  k_prep<<<1120, 256, 0, stream>>>(Wr2, Wr3, Wr4, Wl10, Wl11, Wl20, Wl21,
                                   Wsk0, Wup0, Wres0, Wsk1, Wup1, Wres1,
                                   WTr2, WTr3, WTr4,
                                   Wl10T, Wl11T, Wl20T, Wl21T, WnsT, WnvT);
  k_nodeemb<<<(NN*64+255)/256, 256, 0, stream>>>(attrs, Wc, srP, trP, sdP, tdP);
  k_feat_prep<<<NN*512/256, 256, 0, stream>>>(feats, fs16, fv16);
  k_node_pre2<<<dim3(NB64,13), 256, 0, stream>>>(fs16, fv16, WnsT, WnvT,
                                                 out_sc, up_sp, up_vp, res_s, res_v);
  k_deg<<<(NE+255)/256, 256, 0, stream>>>(eidx, deg);
  k_scan<<<1, 256, 0, stream>>>(deg, offsets);
  k_fill<<<(NE+255)/256, 256, 0, stream>>>(eidx, offsets, cursor, elist);

  for (int c=0; c<NCHUNK; ++c){
    k_tpw<<<CAP/64, 256, 0, stream>>>(elist, eidx, ef, ea,
                                      srP, trP, sdP, tdP,
                                      Wr1, Wd1, Wd2, WTr2, WTr3, WTr4,
                                      offsets, c*NPC, (c+1)*NPC,
                                      tpwp, ybuf, sndbuf, densbuf);
    k_gather<<<NPC/4, 256, 0, stream>>>(tpwp, ybuf, sndbuf, densbuf, up_sp, up_vp,
                                        offsets, c*NPC, msg_s16, msg_v16, density);
  }

  k_post1<<<dim3(NB64,5), 256, 0, stream>>>(msg_s16, msg_v16, density, res_s, res_v,
                                            Wl10T, Wl11T, alphap, betap,
                                            scal16, gate16, vtmp16);
  k_post2<<<dim3(NB64,4), 256, 0, stream>>>(scal16, gate16, vtmp16,
                                            Wl20T, Wl21T, out_msg);
}

// Round 6
// 464.093 us; speedup vs baseline: 1.6975x; 1.2010x over previous
//
#include <hip/hip_runtime.h>
#include <math.h>

#define NN 10000
#define NE 160000
#define MUL 128
#define ADIM 10
#define RADF 8
#define HID 64
#define INV_SQRT3 0.57735026918962576f
#define NB64 157           // ceil(NN/64)

typedef __attribute__((ext_vector_type(8))) short bf16x8;
typedef __attribute__((ext_vector_type(4))) float f32x4;

__device__ __forceinline__ float silu_f(float x){ return x / (1.0f + __expf(-x)); }
__device__ __forceinline__ float sigmoid_f(float x){ return 1.0f / (1.0f + __expf(-x)); }
__device__ __forceinline__ unsigned short f2b(float f){
  union{float f; unsigned u;} v; v.f=f;
  unsigned r = (v.u + 0x7fffu + ((v.u>>16)&1u))>>16;
  return (unsigned short)r;
}
__device__ __forceinline__ float b2f(unsigned short h){
  union{unsigned u; float f;} v; v.u = ((unsigned)h)<<16; return v.f;
}
__device__ __forceinline__ float b2f_lo(unsigned u){
  union{unsigned u; float f;} v; v.u = u<<16; return v.f;
}
__device__ __forceinline__ float b2f_hi(unsigned u){
  union{unsigned u; float f;} v; v.u = u & 0xffff0000u; return v.f;
}

// ---------------- weight combine: Wc[m][10][64], m=0..3 ----------------
__global__ __launch_bounds__(256) void k_wcomb(
    const float* __restrict__ Wsrc, const float* __restrict__ Wtgt,
    const float* __restrict__ Wr1, const float* __restrict__ Wd1,
    float* __restrict__ Wc){
  int tid = threadIdx.x;
  int m = tid>>6, c = tid&63;
  const float* WA = (m&1)? Wtgt : Wsrc;
  const float* WB = (m<2)? Wr1 : Wd1;
  int koff = (m&1)? 136 : 8;
  for (int a=0;a<ADIM;a++){
    float s=0.f;
    for (int k=0;k<128;k++) s += WA[a*128+k]*WB[(koff+k)*64+c];
    Wc[(m*ADIM+a)*64+c] = s;
  }
}

// ---------------- per-node layer1 partials (f32) ----------------
__global__ __launch_bounds__(256) void k_nodeemb(
    const float* __restrict__ attrs, const float* __restrict__ Wc,
    float* __restrict__ srP, float* __restrict__ trP,
    float* __restrict__ sdP, float* __restrict__ tdP){
  int idx = blockIdx.x*256 + threadIdx.x;
  if (idx >= NN*64) return;
  int n = idx>>6, c = idx&63;
  float s0=0,s1=0,s2=0,s3=0;
  #pragma unroll
  for (int a=0;a<ADIM;a++){
    float x = attrs[n*ADIM+a];
    s0 += x*Wc[(0*ADIM+a)*64+c];
    s1 += x*Wc[(1*ADIM+a)*64+c];
    s2 += x*Wc[(2*ADIM+a)*64+c];
    s3 += x*Wc[(3*ADIM+a)*64+c];
  }
  srP[idx]=s0; trP[idx]=s1; sdP[idx]=s2; tdP[idx]=s3;
}

// ---------------- feat prep ----------------
__global__ __launch_bounds__(256) void k_feat_prep(
    const float* __restrict__ feats, unsigned short* __restrict__ fs16,
    unsigned short* __restrict__ fv16){
  int idx = blockIdx.x*256 + threadIdx.x;
  int n = idx >> 9, c = idx & 511;
  float v = feats[idx];
  if (c < 128) fs16[n*128 + c] = f2b(v);
  else {
    int q = c - 128; int u = q/3; int i = q - 3*u;
    fv16[((size_t)n*3 + i)*128 + u] = f2b(v);
  }
}

// ---------------- weight prep: transpose + bf16 cast ----------------
__global__ __launch_bounds__(256) void k_prep(
    const float* __restrict__ Wr2, const float* __restrict__ Wr3,
    const float* __restrict__ Wr4,
    const float* __restrict__ Wl10, const float* __restrict__ Wl11,
    const float* __restrict__ Wl20, const float* __restrict__ Wl21,
    const float* __restrict__ Wsk0, const float* __restrict__ Wup0, const float* __restrict__ Wres0,
    const float* __restrict__ Wsk1, const float* __restrict__ Wup1, const float* __restrict__ Wres1,
    unsigned short* __restrict__ WTr2, unsigned short* __restrict__ WTr3,
    unsigned short* __restrict__ WTr4,
    unsigned short* __restrict__ Wl10T, unsigned short* __restrict__ Wl11T,
    unsigned short* __restrict__ Wl20T, unsigned short* __restrict__ Wl21T,
    unsigned short* __restrict__ WnsT, unsigned short* __restrict__ WnvT){
  int idx = blockIdx.x*256 + threadIdx.x;
  if (idx < 4096){
    int j = idx; int n=j>>6, k=j&63;
    WTr2[j] = f2b(Wr2[k*64+n]);
  } else if (idx < 8192){
    int j = idx-4096; int n=j>>6, k=j&63;
    WTr3[j] = f2b(Wr3[k*64+n]);
  } else if (idx < 40960){
    int j = idx-8192; int n=j>>6, k=j&63;
    WTr4[j] = f2b(Wr4[k*512+n]);
  } else if (idx < 106496){
    int j = idx-40960; int n=j>>8, k=j&255;
    Wl10T[j] = f2b(Wl10[k*256+n]);
  } else if (idx < 139264){
    int j = idx-106496; int n=j>>8, k=j&255;
    Wl11T[j] = f2b(Wl11[k*128+n]);
  } else if (idx < 155648){
    int j = idx-139264; int n=j>>7, k=j&127;
    Wl20T[j] = f2b(Wl20[k*128+n]);
  } else if (idx < 172032){
    int j = idx-155648; int n=j>>7, k=j&127;
    Wl21T[j] = f2b(Wl21[k*128+n]);
  } else if (idx < 237568){
    int j = idx-172032; int n=j>>7, k=j&127;
    float v;
    if (n < 128)      v = Wsk0[k*128+n];
    else if (n < 256) v = Wup0[k*128+(n-128)];
    else              v = Wres0[k*256+(n-256)];
    WnsT[j] = f2b(v);
  } else if (idx < 286720){
    int j = idx-237568; int n=j>>7, k=j&127;
    float v;
    if (n < 128)      v = Wsk1[k*128+n];
    else if (n < 256) v = Wup1[k*128+(n-128)];
    else              v = Wres1[k*128+(n-256)];
    WnvT[j] = f2b(v);
  }
}

// ---------------- K1: per-node precompute via MFMA ----------------
__global__ __launch_bounds__(256) void k_node_pre2(
    const unsigned short* __restrict__ fs16, const unsigned short* __restrict__ fv16,
    const unsigned short* __restrict__ WnsT, const unsigned short* __restrict__ WnvT,
    float* __restrict__ out_sc,
    unsigned* __restrict__ up_sp, unsigned* __restrict__ up_vp,
    float* __restrict__ res_s, float* __restrict__ res_v){
  __shared__ unsigned short fA[64][136];
  int nb = blockIdx.x*64;
  int c = blockIdx.y;
  int g, ntc;
  if (c < 4){ g=0; ntc=c; } else { g = 1 + (c-4)/3; ntc = (c-4)%3; }
  int tid = threadIdx.x;
  int w = tid>>6, l = tid&63, m0 = w*16, lr = l&15, lg = l>>4;
  for (int idx=tid; idx<64*16; idx+=256){
    int row = idx>>4, s8 = idx&15;
    int n = min(nb+row, NN-1);
    const unsigned short* src = (g==0) ? &fs16[(size_t)n*128 + s8*8]
                                       : &fv16[((size_t)n*3 + (g-1))*128 + s8*8];
    *(uint4*)&fA[row][s8*8] = *(const uint4*)src;
  }
  __syncthreads();
  const unsigned short* WT = ((g==0)? WnsT : WnvT) + (size_t)ntc*128*128;
  f32x4 acc[8];
  #pragma unroll
  for (int t=0;t<8;t++) acc[t]=(f32x4)(0.f);
  #pragma unroll
  for (int kb=0;kb<4;kb++){
    bf16x8 a = *(const bf16x8*)&fA[m0+lr][kb*32 + lg*8];
    #pragma unroll
    for (int t=0;t<8;t++){
      bf16x8 b = *(const bf16x8*)&WT[(size_t)(t*16+lr)*128 + kb*32 + lg*8];
      acc[t] = __builtin_amdgcn_mfma_f32_16x16x32_bf16(a, b, acc[t], 0,0,0);
    }
  }
  #pragma unroll
  for (int t=0;t<8;t++){
    #pragma unroll
    for (int r=0;r<4;r++){
      int col = (ntc*8+t)*16 + lr;
      int row = m0 + lg*4 + r;
      int n = nb + row;
      if (n < NN){
        float v = acc[t][r];
        if (g==0){
          if (col < 128)      out_sc[(size_t)n*512 + col] = v;
          else if (col < 256){
            int cc = col-128;
            ((unsigned short*)up_sp)[((size_t)n*64 + (cc&63))*2 + (cc>>6)] = f2b(v);
          } else              res_s[(size_t)n*256 + col-256] = v;
        } else {
          int i = g-1;
          if (col < 128)      out_sc[(size_t)n*512 + 128 + col*3 + i] = v;
          else if (col < 256){
            int cc = col-128;
            ((unsigned short*)up_vp)[(((size_t)n*3+i)*64 + (cc&63))*2 + (cc>>6)] = f2b(v);
          } else              res_v[((size_t)n*3+i)*128 + col-256] = v;
        }
      }
    }
  }
}

// ---------------- CSR build ----------------
__global__ __launch_bounds__(256) void k_deg(const int* __restrict__ eidx, int* __restrict__ deg){
  int i = blockIdx.x*256+threadIdx.x;
  if (i<NE) atomicAdd(&deg[eidx[2*i+1]],1);
}
__global__ __launch_bounds__(256) void k_scan(const int* __restrict__ deg, int* __restrict__ offsets){
  __shared__ int part[256];
  int t = threadIdx.x; int base = t*40;
  int s=0;
  for (int k=0;k<40;k++){ int idx=base+k; if (idx<NN) s+=deg[idx]; }
  part[t]=s; __syncthreads();
  if (t==0){ int run=0; for (int i=0;i<256;i++){ int v=part[i]; part[i]=run; run+=v; } }
  __syncthreads();
  int run = part[t];
  for (int k=0;k<40;k++){
    int idx=base+k;
    if (idx<=NN) offsets[idx]=run;
    if (idx<NN) run+=deg[idx];
  }
}
__global__ __launch_bounds__(256) void k_fill(const int* __restrict__ eidx, const int* __restrict__ offsets,
                                              int* __restrict__ cursor, int* __restrict__ elist){
  int i = blockIdx.x*256+threadIdx.x;
  if (i<NE){ int r = eidx[2*i+1]; int p = atomicAdd(&cursor[r],1); elist[offsets[r]+p]=i; }
}

// ---------------- K2: edge MLP (layer1 folded) ----------------
__global__ __launch_bounds__(256) void k_tpw(
    const int* __restrict__ elist, const int* __restrict__ eidx,
    const float* __restrict__ ef, const float* __restrict__ ea,
    const float* __restrict__ srP, const float* __restrict__ trP,
    const float* __restrict__ sdP, const float* __restrict__ tdP,
    const float* __restrict__ Wr1, const float* __restrict__ Wd1, const float* __restrict__ Wd2,
    const unsigned short* __restrict__ WTr2, const unsigned short* __restrict__ WTr3,
    const unsigned short* __restrict__ WTr4,
    const int* __restrict__ offsets, int nstart, int nend, int cap,
    unsigned* __restrict__ tpwp, float4* __restrict__ ybuf,
    int* __restrict__ sndbuf, float* __restrict__ densbuf){
  __shared__ unsigned short hA[64][72];
  __shared__ unsigned short hB[64][72];
  __shared__ unsigned short hC[64][72];
  __shared__ float efs[64][8];
  __shared__ int s_snd[64], s_rcv[64];
  int ebase = offsets[nstart];
  int eend  = min(offsets[nend], ebase + cap);
  int i0 = ebase + blockIdx.x*64;
  if (i0 >= eend) return;
  int nrows = min(64, eend - i0);
  int tid = threadIdx.x;
  int w = tid>>6, l = tid&63, m0 = w*16, lr = l&15, lg = l>>4;
  if (tid < 64){
    int ii = min(i0 + tid, eend-1);
    int e = elist[ii];
    int sn = eidx[2*e], rc = eidx[2*e+1];
    s_snd[tid]=sn; s_rcv[tid]=rc;
    if (tid < nrows){
      int li = i0 - ebase + tid;
      sndbuf[li] = sn;
      ybuf[li] = ((const float4*)ea)[e];
    }
  }
  if (tid < 128){
    int r = tid>>1, hf = tid&1;
    int e = elist[min(i0+r, eend-1)];
    *(float4*)&efs[r][hf*4] = *(const float4*)&ef[(size_t)e*8 + hf*4];
  }
  __syncthreads();
  // ---- layer1 (VALU, f32) ----
  {
    float wr[8], wd[8];
    #pragma unroll
    for (int k=0;k<8;k++){ wr[k]=Wr1[k*64+l]; wd[k]=Wd1[k*64+l]; }
    float wd2c = Wd2[l];
    #pragma unroll
    for (int j=0;j<16;j++){
      int r = m0+j;
      int sn = s_snd[r], rc = s_rcv[r];
      float h  = srP[sn*64+l] + trP[rc*64+l];
      float hd = sdP[sn*64+l] + tdP[rc*64+l];
      #pragma unroll
      for (int k=0;k<8;k++){ float ek=efs[r][k]; h += ek*wr[k]; hd += ek*wd[k]; }
      hA[r][l] = f2b(silu_f(h));
      float sv = silu_f(hd)*wd2c;
      #pragma unroll
      for (int m=32;m;m>>=1) sv += __shfl_xor(sv, m);
      if (l==0 && j+m0 < nrows) densbuf[i0 - ebase + r] = tanhf(sv*sv);
    }
  }
  // ---- layer2 ----
  f32x4 acc[4];
  #pragma unroll
  for (int nt=0;nt<4;nt++) acc[nt]=(f32x4)(0.f);
  for (int kb=0;kb<2;kb++){
    bf16x8 a = *(const bf16x8*)&hA[m0+lr][kb*32 + lg*8];
    #pragma unroll
    for (int nt=0;nt<4;nt++){
      bf16x8 b = *(const bf16x8*)&WTr2[(nt*16+lr)*64 + kb*32 + lg*8];
      acc[nt] = __builtin_amdgcn_mfma_f32_16x16x32_bf16(a, b, acc[nt], 0,0,0);
    }
  }
  #pragma unroll
  for (int nt=0;nt<4;nt++)
    #pragma unroll
    for (int r=0;r<4;r++)
      hB[m0+lg*4+r][nt*16+lr] = f2b(silu_f(acc[nt][r]));
  // ---- layer3 ----
  #pragma unroll
  for (int nt=0;nt<4;nt++) acc[nt]=(f32x4)(0.f);
  for (int kb=0;kb<2;kb++){
    bf16x8 a = *(const bf16x8*)&hB[m0+lr][kb*32 + lg*8];
    #pragma unroll
    for (int nt=0;nt<4;nt++){
      bf16x8 b = *(const bf16x8*)&WTr3[(nt*16+lr)*64 + kb*32 + lg*8];
      acc[nt] = __builtin_amdgcn_mfma_f32_16x16x32_bf16(a, b, acc[nt], 0,0,0);
    }
  }
  #pragma unroll
  for (int nt=0;nt<4;nt++)
    #pragma unroll
    for (int r=0;r<4;r++)
      hA[m0+lg*4+r][nt*16+lr] = f2b(silu_f(acc[nt][r]));
  // ---- layer4: packed u32 store ----
  int li0 = i0 - ebase + m0;
  (void)li0;
  for (int G=0; G<4; G++){
    f32x4 aE[4], aO[4];
    #pragma unroll
    for (int nt=0;nt<4;nt++){ aE[nt]=(f32x4)(0.f); aO[nt]=(f32x4)(0.f); }
    for (int kb=0;kb<2;kb++){
      bf16x8 a = *(const bf16x8*)&hA[m0+lr][kb*32 + lg*8];
      #pragma unroll
      for (int nt=0;nt<4;nt++){
        bf16x8 bE = *(const bf16x8*)&WTr4[((2*G)*64+nt*16+lr)*64 + kb*32 + lg*8];
        bf16x8 bO = *(const bf16x8*)&WTr4[((2*G+1)*64+nt*16+lr)*64 + kb*32 + lg*8];
        aE[nt] = __builtin_amdgcn_mfma_f32_16x16x32_bf16(a, bE, aE[nt], 0,0,0);
        aO[nt] = __builtin_amdgcn_mfma_f32_16x16x32_bf16(a, bO, aO[nt], 0,0,0);
      }
    }
    #pragma unroll
    for (int nt=0;nt<4;nt++)
      #pragma unroll
      for (int r=0;r<4;r++){
        hB[m0+lg*4+r][nt*16+lr] = f2b(aE[nt][r]);
        hC[m0+lg*4+r][nt*16+lr] = f2b(aO[nt][r]);
      }
    {
      int row = m0 + (l>>2), seg = l&3;
      if (row < nrows){
        const unsigned short* pb = &hB[row][seg*16];
        const unsigned short* pc = &hC[row][seg*16];
        unsigned o[16];
        #pragma unroll
        for (int t=0;t<16;t++) o[t] = (unsigned)pb[t] | ((unsigned)pc[t]<<16);
        size_t base = (size_t)(i0 - ebase + row)*256 + G*64 + seg*16;
        *(uint4*)&tpwp[base+0]  = *(uint4*)&o[0];
        *(uint4*)&tpwp[base+4]  = *(uint4*)&o[4];
        *(uint4*)&tpwp[base+8]  = *(uint4*)&o[8];
        *(uint4*)&tpwp[base+12] = *(uint4*)&o[12];
      }
    }
  }
}

// ---------------- K3: CSR gather, packed u32 loads ----------------
__global__ __launch_bounds__(256) void k_gather(
    const unsigned* __restrict__ tpwp, const float4* __restrict__ ybuf,
    const int* __restrict__ sndbuf, const float* __restrict__ densbuf,
    const unsigned* __restrict__ up_sp, const unsigned* __restrict__ up_vp,
    const int* __restrict__ offsets, int nstart,
    unsigned short* __restrict__ msg_s16, unsigned short* __restrict__ msg_v16,
    float* __restrict__ density){
  int w = threadIdx.x>>6, l = threadIdx.x&63;
  int n = nstart + blockIdx.x*4 + w;
  if (n >= NN) return;
  int ebase = offsets[nstart];
  int s0 = offsets[n], s1 = offsets[n+1];
  float mA0=0,mA1=0,mD0=0,mD1=0;
  float mB00=0,mB01=0,mB10=0,mB11=0,mB20=0,mB21=0;
  float mC00=0,mC01=0,mC10=0,mC11=0,mC20=0,mC21=0;
  float dsum=0;
  #pragma unroll 2
  for (int i=s0;i<s1;++i){
    int li = i - ebase;
    int sn = sndbuf[li];
    float4 y = ybuf[li];
    dsum += densbuf[li];
    const unsigned* tp = tpwp + (size_t)li*256;
    unsigned uA = tp[l], uB = tp[64+l], uC = tp[128+l], uD = tp[192+l];
    float wA0=b2f_lo(uA), wA1=b2f_hi(uA);
    float wB0=b2f_lo(uB), wB1=b2f_hi(uB);
    float wC0=b2f_lo(uC), wC1=b2f_hi(uC);
    float wD0=b2f_lo(uD), wD1=b2f_hi(uD);
    unsigned us = up_sp[(size_t)sn*64 + l];
    float xs0=b2f_lo(us), xs1=b2f_hi(us);
    unsigned uv0 = up_vp[((size_t)sn*3+0)*64 + l];
    unsigned uv1 = up_vp[((size_t)sn*3+1)*64 + l];
    unsigned uv2 = up_vp[((size_t)sn*3+2)*64 + l];
    float xv00=b2f_lo(uv0), xv01=b2f_hi(uv0);
    float xv10=b2f_lo(uv1), xv11=b2f_hi(uv1);
    float xv20=b2f_lo(uv2), xv21=b2f_hi(uv2);
    mA0 += wA0*xs0*y.x; mA1 += wA1*xs1*y.x;
    float dot0 = xv00*y.y + xv10*y.z + xv20*y.w;
    float dot1 = xv01*y.y + xv11*y.z + xv21*y.w;
    mD0 += wD0*dot0; mD1 += wD1*dot1;
    float b0 = wB0*xs0, b1 = wB1*xs1;
    mB00 += b0*y.y; mB01 += b1*y.y;
    mB10 += b0*y.z; mB11 += b1*y.z;
    mB20 += b0*y.w; mB21 += b1*y.w;
    float c0 = wC0*y.x, c1 = wC1*y.x;
    mC00 += c0*xv00; mC01 += c1*xv01;
    mC10 += c0*xv10; mC11 += c1*xv11;
    mC20 += c0*xv20; mC21 += c1*xv21;
  }
  unsigned short* ms = msg_s16 + (size_t)n*256;
  ms[l]=f2b(mA0); ms[64+l]=f2b(mA1);
  ms[128+l]=f2b(mD0*INV_SQRT3); ms[192+l]=f2b(mD1*INV_SQRT3);
  unsigned short* mv = msg_v16 + (size_t)n*768;
  mv[l]=f2b(mB00);     mv[64+l]=f2b(mB01);  mv[128+l]=f2b(mC00); mv[192+l]=f2b(mC01);
  mv[256+l]=f2b(mB10); mv[320+l]=f2b(mB11); mv[384+l]=f2b(mC10); mv[448+l]=f2b(mC11);
  mv[512+l]=f2b(mB20); mv[576+l]=f2b(mB21); mv[640+l]=f2b(mC20); mv[704+l]=f2b(mC21);
  if (l==0) density[n]=dsum;
}

// ---------------- K4a: lin1 for all 5 N=128 chunks. grid (NB64, 5) ----------------
__global__ __launch_bounds__(256) void k_post1(
    const unsigned short* __restrict__ msg_s16, const unsigned short* __restrict__ msg_v16,
    const float* __restrict__ density,
    const float* __restrict__ res_s, const float* __restrict__ res_v,
    const unsigned short* __restrict__ Wl10T, const unsigned short* __restrict__ Wl11T,
    const float* __restrict__ alphap, const float* __restrict__ betap,
    unsigned short* __restrict__ scal16, unsigned short* __restrict__ gate16,
    unsigned short* __restrict__ vtmp16){
  __shared__ unsigned short sm[64][264];
  __shared__ float sden[64];
  int nb = blockIdx.x*64, y = blockIdx.y;
  int tid = threadIdx.x;
  int w = tid>>6, l = tid&63, m0 = w*16, lr = l&15, lg = l>>4;
  for (int idx=tid; idx<64*32; idx+=256){
    int row = idx>>5, s8 = idx&31;
    int n = min(nb+row, NN-1);
    const unsigned short* src = (y<2)? &msg_s16[(size_t)n*256 + s8*8]
                                     : &msg_v16[(size_t)n*768 + (y-2)*256 + s8*8];
    *(uint4*)&sm[row][s8*8] = *(const uint4*)src;
  }
  if (tid < 64){
    int n = min(nb+tid, NN-1);
    sden[tid] = density[n]*betap[0] + alphap[0]*20.0f;
  }
  __syncthreads();
  const unsigned short* BT = (y<2)? (Wl10T + (size_t)y*128*256) : Wl11T;
  f32x4 acc[8];
  #pragma unroll
  for (int t=0;t<8;t++) acc[t]=(f32x4)(0.f);
  for (int kb=0;kb<8;kb++){
    bf16x8 a = *(const bf16x8*)&sm[m0+lr][kb*32 + lg*8];
    #pragma unroll
    for (int t=0;t<8;t++){
      bf16x8 b = *(const bf16x8*)&BT[(size_t)(t*16+lr)*256 + kb*32 + lg*8];
      acc[t] = __builtin_amdgcn_mfma_f32_16x16x32_bf16(a, b, acc[t], 0,0,0);
    }
  }
  #pragma unroll
  for (int t=0;t<8;t++){
    #pragma unroll
    for (int r=0;r<4;r++){
      int col = t*16+lr;
      int row = m0 + lg*4 + r;
      int n = nb + row;
      if (n < NN){
        float v = acc[t][r]/sden[row];
        if (y==0){
          v += res_s[(size_t)n*256 + col];
          scal16[(size_t)n*128 + col] = f2b(silu_f(v));
        } else if (y==1){
          v += res_s[(size_t)n*256 + 128 + col];
          gate16[(size_t)n*128 + col] = f2b(sigmoid_f(v));
        } else {
          int i = y-2;
          v += res_v[((size_t)n*3+i)*128 + col];
          vtmp16[((size_t)i*NN + n)*128 + col] = f2b(v);
        }
      }
    }
  }
}

// ---------------- K4b: lin2 for 4 output components. grid (NB64, 4) ----------------
__global__ __launch_bounds__(256) void k_post2(
    const unsigned short* __restrict__ scal16, const unsigned short* __restrict__ gate16,
    const unsigned short* __restrict__ vtmp16,
    const unsigned short* __restrict__ Wl20T, const unsigned short* __restrict__ Wl21T,
    float* __restrict__ out_msg){
  __shared__ unsigned short sA[64][136];
  int nb = blockIdx.x*64, y = blockIdx.y;
  int tid = threadIdx.x;
  int w = tid>>6, l = tid&63, m0 = w*16, lr = l&15, lg = l>>4;
  for (int idx=tid; idx<64*16; idx+=256){
    int row = idx>>4, s8 = idx&15;
    int n = min(nb+row, NN-1);
    if (y==0){
      *(uint4*)&sA[row][s8*8] = *(const uint4*)&scal16[(size_t)n*128 + s8*8];
    } else {
      int i = y-1;
      uint4 va = *(const uint4*)&vtmp16[((size_t)i*NN + n)*128 + s8*8];
      uint4 vg = *(const uint4*)&gate16[(size_t)n*128 + s8*8];
      const unsigned short* pa = (const unsigned short*)&va;
      const unsigned short* pg = (const unsigned short*)&vg;
      unsigned short o[8];
      #pragma unroll
      for (int j=0;j<8;j++) o[j] = f2b(b2f(pa[j])*b2f(pg[j]));
      *(uint4*)&sA[row][s8*8] = *(const uint4*)o;
    }
  }
  __syncthreads();
  const unsigned short* BT = (y==0)? Wl20T : Wl21T;
  f32x4 acc[8];
  #pragma unroll
  for (int t=0;t<8;t++) acc[t]=(f32x4)(0.f);
  #pragma unroll
  for (int kb=0;kb<4;kb++){
    bf16x8 a = *(const bf16x8*)&sA[m0+lr][kb*32 + lg*8];
    #pragma unroll
    for (int t=0;t<8;t++){
      bf16x8 b = *(const bf16x8*)&BT[(size_t)(t*16+lr)*128 + kb*32 + lg*8];
      acc[t] = __builtin_amdgcn_mfma_f32_16x16x32_bf16(a, b, acc[t], 0,0,0);
    }
  }
  #pragma unroll
  for (int t=0;t<8;t++){
    #pragma unroll
    for (int r=0;r<4;r++){
      int col = t*16+lr;
      int n = nb + m0 + lg*4 + r;
      if (n < NN) out_msg[(size_t)n*512 + col*4 + y] = acc[t][r];
    }
  }
}

extern "C" void kernel_launch(void* const* d_in, const int* in_sizes, int n_in,
                              void* d_out, int out_size, void* d_ws, size_t ws_size,
                              hipStream_t stream){
  (void)in_sizes; (void)n_in; (void)out_size;
  const float* attrs = (const float*)d_in[0];
  const float* feats = (const float*)d_in[1];
  const float* ea    = (const float*)d_in[2];
  const float* ef    = (const float*)d_in[3];
  const float* Wsrc  = (const float*)d_in[4];
  const float* Wtgt  = (const float*)d_in[5];
  const float* Wup0  = (const float*)d_in[6];
  const float* Wup1  = (const float*)d_in[7];
  const float* Wsk0  = (const float*)d_in[8];
  const float* Wsk1  = (const float*)d_in[9];
  const float* Wres0 = (const float*)d_in[10];
  const float* Wres1 = (const float*)d_in[11];
  const float* Wl10  = (const float*)d_in[12];
  const float* Wl11  = (const float*)d_in[13];
  const float* Wl20  = (const float*)d_in[14];
  const float* Wl21  = (const float*)d_in[15];
  const float* Wr1   = (const float*)d_in[16];
  const float* Wr2   = (const float*)d_in[17];
  const float* Wr3   = (const float*)d_in[18];
  const float* Wr4   = (const float*)d_in[19];
  const float* Wd1   = (const float*)d_in[20];
  const float* Wd2   = (const float*)d_in[21];
  const float* alphap= (const float*)d_in[22];
  const float* betap = (const float*)d_in[23];
  const int*   eidx  = (const int*)d_in[24];

  // --- adaptive chunking: pick the smallest chunk count whose tpw buffer fits ws ---
  // fixed (non-cap-dependent) bytes, with 256B alignment slack per buffer:
  const size_t fixed_bytes =
      (size_t)NN*256*2 + (size_t)NN*768*2 + (size_t)NN*256*4 + (size_t)NN*384*4 +
      (size_t)NN*4 + (size_t)NN*64*4 + (size_t)NN*192*4 +
      (size_t)NN*128*2 + (size_t)NN*384*2 +
      4*(size_t)NN*64*4 + 4*ADIM*64*4 + (size_t)NN*128*2 +
      (4096+4096+32768+65536+32768+16384+16384+65536+49152)*2 +
      (10240+10240+10256)*4 + (size_t)NE*4 + 64*256;
  // per-edge cap bytes: tpwp 1024 + ybuf 16 + densbuf 4 + sndbuf 4 = 1048
  int nchunk, npc, cap;
  if (fixed_bytes + (size_t)NE*1048 + 65536 <= ws_size){ nchunk=1; npc=NN;   cap=NE;    }
  else if (fixed_bytes + 81920ULL*1048 + 65536 <= ws_size){ nchunk=2; npc=5000; cap=81920; }
  else { nchunk=4; npc=2500; cap=44032; }

  char* p = (char*)d_ws;
  auto alloc = [&](size_t bytes)->char*{ char* r=p; p += (bytes+255)&~(size_t)255; return r; };
  unsigned* tpwp  = (unsigned*)alloc((size_t)cap*256*4);
  unsigned short* msg_s16 = (unsigned short*)alloc((size_t)NN*256*2);
  unsigned short* msg_v16 = (unsigned short*)alloc((size_t)NN*768*2);
  float*  res_s   = (float*)alloc((size_t)NN*256*4);
  float*  res_v   = (float*)alloc((size_t)NN*384*4);
  float*  density = (float*)alloc((size_t)NN*4);
  float4* ybuf    = (float4*)alloc((size_t)cap*16);
  float*  densbuf = (float*)alloc((size_t)cap*4);
  int*    sndbuf  = (int*)alloc((size_t)cap*4);
  unsigned* up_sp = (unsigned*)alloc((size_t)NN*64*4);
  unsigned* up_vp = (unsigned*)alloc((size_t)NN*192*4);
  unsigned short* fs16 = (unsigned short*)alloc((size_t)NN*128*2);
  unsigned short* fv16 = (unsigned short*)alloc((size_t)NN*384*2);
  float* srP = (float*)alloc((size_t)NN*64*4);
  float* trP = (float*)alloc((size_t)NN*64*4);
  float* sdP = (float*)alloc((size_t)NN*64*4);
  float* tdP = (float*)alloc((size_t)NN*64*4);
  float* Wc  = (float*)alloc(4*ADIM*64*4);
  unsigned short* gate16 = (unsigned short*)alloc((size_t)NN*128*2);
  unsigned short* WTr2 = (unsigned short*)alloc(4096*2);
  unsigned short* WTr3 = (unsigned short*)alloc(4096*2);
  unsigned short* WTr4 = (unsigned short*)alloc(32768*2);
  unsigned short* Wl10T = (unsigned short*)alloc(65536*2);
  unsigned short* Wl11T = (unsigned short*)alloc(32768*2);
  unsigned short* Wl20T = (unsigned short*)alloc(16384*2);
  unsigned short* Wl21T = (unsigned short*)alloc(16384*2);
  unsigned short* WnsT  = (unsigned short*)alloc(65536*2);
  unsigned short* WnvT  = (unsigned short*)alloc(49152*2);
  int* deg     = (int*)alloc(10240*4);
  int* cursor  = (int*)alloc(10240*4);
  int* offsets = (int*)alloc(10256*4);
  int* elist   = (int*)alloc((size_t)NE*4);

  unsigned short* scal16 = fs16;   // NN*128, fs16 dead after k_node_pre2
  unsigned short* vtmp16 = fv16;   // 3*NN*128, fv16 dead after k_node_pre2

  float* out_msg = (float*)d_out;               // NN*512
  float* out_sc  = out_msg + (size_t)NN*512;    // NN*512

  hipMemsetAsync(deg, 0, 2*10240*sizeof(int), stream);

  k_wcomb<<<1, 256, 0, stream>>>(Wsrc, Wtgt, Wr1, Wd1, Wc);
  k_prep<<<1120, 256, 0, stream>>>(Wr2, Wr3, Wr4, Wl10, Wl11, Wl20, Wl21,
                                   Wsk0, Wup0, Wres0, Wsk1, Wup1, Wres1,
                                   WTr2, WTr3, WTr4,
                                   Wl10T, Wl11T, Wl20T, Wl21T, WnsT, WnvT);
  k_nodeemb<<<(NN*64+255)/256, 256, 0, stream>>>(attrs, Wc, srP, trP, sdP, tdP);
  k_feat_prep<<<NN*512/256, 256, 0, stream>>>(feats, fs16, fv16);
  k_node_pre2<<<dim3(NB64,13), 256, 0, stream>>>(fs16, fv16, WnsT, WnvT,
                                                 out_sc, up_sp, up_vp, res_s, res_v);
  k_deg<<<(NE+255)/256, 256, 0, stream>>>(eidx, deg);
  k_scan<<<1, 256, 0, stream>>>(deg, offsets);
  k_fill<<<(NE+255)/256, 256, 0, stream>>>(eidx, offsets, cursor, elist);

  int tpw_blocks = (cap+63)/64;
  for (int c=0; c<nchunk; ++c){
    k_tpw<<<tpw_blocks, 256, 0, stream>>>(elist, eidx, ef, ea,
                                          srP, trP, sdP, tdP,
                                          Wr1, Wd1, Wd2, WTr2, WTr3, WTr4,
                                          offsets, c*npc, (c+1)*npc, cap,
                                          tpwp, ybuf, sndbuf, densbuf);
    k_gather<<<npc/4, 256, 0, stream>>>(tpwp, ybuf, sndbuf, densbuf, up_sp, up_vp,
                                        offsets, c*npc, msg_s16, msg_v16, density);
  }

  k_post1<<<dim3(NB64,5), 256, 0, stream>>>(msg_s16, msg_v16, density, res_s, res_v,
                                            Wl10T, Wl11T, alphap, betap,
                                            scal16, gate16, vtmp16);
  k_post2<<<dim3(NB64,4), 256, 0, stream>>>(scal16, gate16, vtmp16,
                                            Wl20T, Wl21T, out_msg);
}